// Round 3
// baseline (569.449 us; speedup 1.0000x reference)
//
#include <hip/hip_runtime.h>

// ---------------------------------------------------------------------------
// Res_NL pansharpening network, B=1, H=W=128, f32 in/out.
//   features_k : uf/pf 3x3 convs + nine 1x1 transforms (2 output groups)
//   heads_k    : 3 attention heads, LDS-staged, 2 threads/pixel (k-row split)
//   assemble_k : mlp combine + resu/respan convs (5 output groups)
//   conv42_k   : LDS-tiled direct 3x3 conv, CIN=42 (res blocks + recon)
// ---------------------------------------------------------------------------

#define DEV __device__ __forceinline__

constexpr int N = 128 * 128;   // 16384 pixels

// ---- workspace layout (float offsets) -------------------------------------
constexpr int OFF_PHI1 =   0 * N;   // 3 ch
constexpr int OFF_TH1  =   3 * N;   // 3 ch
constexpr int OFF_PHI2 =   6 * N;   // 5 ch
constexpr int OFF_TH2  =  11 * N;   // 5 ch
constexpr int OFF_PHI3 =  16 * N;   // 8 ch
constexpr int OFF_TH3  =  24 * N;   // 8 ch
constexpr int OFF_G1   =  32 * N;   // 5 ch
constexpr int OFF_G2   =  37 * N;   // 5 ch
constexpr int OFF_G3   =  42 * N;   // 5 ch
constexpr int OFF_X    =  47 * N;   // 42 ch
// OH overlap F: OH live only heads->assemble; F first written after assemble.
constexpr int OFF_OH1  =  89 * N;   // 5 ch
constexpr int OFF_OH2  =  94 * N;   // 5 ch
constexpr int OFF_OH3  =  99 * N;   // 5 ch
constexpr int OFF_F    =  89 * N;   // 42 ch (res-block temp)

DEV bool inb(int y, int x) { return (unsigned)y < 128u && (unsigned)x < 128u; }

// ---------------------------------------------------------------------------
// K1: features. grid (64, 2). Group 0 writes phi2/th2/g1/g2/g3 (uf only);
// group 1 writes phi1/th1 (pf) and phi3/th3 (uf++pf). uf conv duplicated.
// ---------------------------------------------------------------------------
__global__ __launch_bounds__(256) void features_k(
    const float* __restrict__ u, const float* __restrict__ pan,
    const float* __restrict__ wnlu, const float* __restrict__ wnlpan,
    const float* __restrict__ gphi, const float* __restrict__ gth,
    const float* __restrict__ gg, const float* __restrict__ sphi,
    const float* __restrict__ sth, const float* __restrict__ sg,
    const float* __restrict__ mphi, const float* __restrict__ mth,
    const float* __restrict__ mg, float* __restrict__ ws) {
    const int p = blockIdx.x * 256 + threadIdx.x;
    const int y = p >> 7, x = p & 127;

    float uf[5] = {0, 0, 0, 0, 0};
    for (int ic = 0; ic < 8; ++ic) {
#pragma unroll
        for (int i = 0; i < 3; ++i) {
            int yy = y + i - 1;
#pragma unroll
            for (int j = 0; j < 3; ++j) {
                int xx = x + j - 1;
                float v = inb(yy, xx) ? u[ic * N + yy * 128 + xx] : 0.f;
#pragma unroll
                for (int o = 0; o < 5; ++o)
                    uf[o] = fmaf(v, wnlu[(o * 8 + ic) * 9 + i * 3 + j], uf[o]);
            }
        }
    }
    if (blockIdx.y == 0) {
#pragma unroll
        for (int o = 0; o < 5; ++o) {
            float a = 0, b = 0, c1 = 0, c2 = 0, c3 = 0;
#pragma unroll
            for (int i = 0; i < 5; ++i) {
                a  = fmaf(sphi[o * 5 + i], uf[i], a);
                b  = fmaf(sth [o * 5 + i], uf[i], b);
                c1 = fmaf(gg  [o * 5 + i], uf[i], c1);
                c2 = fmaf(sg  [o * 5 + i], uf[i], c2);
                c3 = fmaf(mg  [o * 5 + i], uf[i], c3);
            }
            ws[OFF_PHI2 + o * N + p] = a;
            ws[OFF_TH2  + o * N + p] = b;
            ws[OFF_G1   + o * N + p] = c1;
            ws[OFF_G2   + o * N + p] = c2;
            ws[OFF_G3   + o * N + p] = c3;
        }
    } else {
        float pf[3] = {0, 0, 0};
#pragma unroll
        for (int i = 0; i < 3; ++i) {
            int yy = y + i - 1;
#pragma unroll
            for (int j = 0; j < 3; ++j) {
                int xx = x + j - 1;
                float v = inb(yy, xx) ? pan[yy * 128 + xx] : 0.f;
#pragma unroll
                for (int o = 0; o < 3; ++o)
                    pf[o] = fmaf(v, wnlpan[o * 9 + i * 3 + j], pf[o]);
            }
        }
        float cat[8] = {uf[0], uf[1], uf[2], uf[3], uf[4], pf[0], pf[1], pf[2]};
#pragma unroll
        for (int o = 0; o < 3; ++o) {
            float a = 0, b = 0;
#pragma unroll
            for (int i = 0; i < 3; ++i) {
                a = fmaf(gphi[o * 3 + i], pf[i], a);
                b = fmaf(gth [o * 3 + i], pf[i], b);
            }
            ws[OFF_PHI1 + o * N + p] = a;
            ws[OFF_TH1  + o * N + p] = b;
        }
#pragma unroll
        for (int o = 0; o < 8; ++o) {
            float a = 0, b = 0;
#pragma unroll
            for (int i = 0; i < 8; ++i) {
                a = fmaf(mphi[o * 8 + i], cat[i], a);
                b = fmaf(mth [o * 8 + i], cat[i], b);
            }
            ws[OFF_PHI3 + o * N + p] = a;
            ws[OFF_TH3  + o * N + p] = b;
        }
    }
}

// ---------------------------------------------------------------------------
// K2: attention heads, LDS-staged, tile 16 wide x 8 tall, 256 threads =
// 2 threads per pixel. Half m in {0,1} computes neighbor rows d = 3m+{0..3};
// m=1's d=3 row is dummy (uniform control flow), ownership: m0 -> d0..3,
// m1 -> d4..6. Softmax/PV combined across halves via __shfl_xor(.,32)
// (both halves of a pixel sit in the same wave64).
// ---------------------------------------------------------------------------
template <int C, int P>
DEV void head_tile(const float* __restrict__ phi, const float* __restrict__ theta,
                   const float* __restrict__ g, float* __restrict__ oh,
                   float* __restrict__ smem, int ty0, int tx0, int t) {
    constexpr int PR  = P / 2;
    constexpr int H3  = 3 + PR;          // phi halo
    constexpr int W   = 6 + P;           // phi band width (dx+j range)
    constexpr int TTH = 8 + 2 * PR, TTW = 16 + 2 * PR;
    constexpr int PTH = 8 + 2 * H3, PTW = 16 + 2 * H3;
    constexpr int GTH = 14, GTW = 22;    // g halo 3

    float* sT = smem;
    float* sP = sT + C * TTH * TTW;
    float* sG = sP + C * PTH * PTW;

    for (int i = t; i < C * TTH * TTW; i += 256) {
        int c = i / (TTH * TTW), rem = i % (TTH * TTW);
        int r = rem / TTW, cc = rem % TTW;
        int gy = ty0 - PR + r, gx = tx0 - PR + cc;
        sT[i] = inb(gy, gx) ? theta[c * N + gy * 128 + gx] : 0.f;
    }
    for (int i = t; i < C * PTH * PTW; i += 256) {
        int c = i / (PTH * PTW), rem = i % (PTH * PTW);
        int r = rem / PTW, cc = rem % PTW;
        int gy = ty0 - H3 + r, gx = tx0 - H3 + cc;
        sP[i] = inb(gy, gx) ? phi[c * N + gy * 128 + gx] : 0.f;
    }
    for (int i = t; i < 5 * GTH * GTW; i += 256) {
        int c = i / (GTH * GTW), rem = i % (GTH * GTW);
        int r = rem / GTW, cc = rem % GTW;
        int gy = ty0 - 3 + r, gx = tx0 - 3 + cc;
        sG[i] = inb(gy, gx) ? g[c * N + gy * 128 + gx] : 0.f;
    }
    __syncthreads();

    const int wave = t >> 6, lane = t & 63, m = lane >> 5;
    const int pidx = (lane & 31) | (wave << 5);     // 0..127
    const int py = pidx >> 4, px = pidx & 15;
    const int gy = ty0 + py, gx = tx0 + px;
    const int dbase = m * 3;

    float s[28];
#pragma unroll
    for (int k = 0; k < 28; ++k) s[k] = 0.f;

    for (int c = 0; c < C; ++c) {
        const float* tc = sT + c * TTH * TTW;
        const float* pc = sP + c * PTH * PTW;
        float T[P][P];
#pragma unroll
        for (int i = 0; i < P; ++i)
#pragma unroll
            for (int j = 0; j < P; ++j)
                T[i][j] = tc[(py + i) * TTW + px + j];
        float R[P][W];
#pragma unroll
        for (int r = 0; r < P; ++r)
#pragma unroll
            for (int w = 0; w < W; ++w)
                R[r][w] = pc[(py + dbase + r) * PTW + px + w];
#pragma unroll
        for (int dd = 0; dd < 4; ++dd) {
#pragma unroll
            for (int dx = 0; dx < 7; ++dx) {
                float a = 0.f;
#pragma unroll
                for (int i = 0; i < P; ++i)
#pragma unroll
                    for (int j = 0; j < P; ++j)
                        a = fmaf(T[i][j], R[i][dx + j], a);
                s[dd * 7 + dx] += a;
            }
            if (dd < 3) {
#pragma unroll
                for (int r = 0; r < P - 1; ++r)
#pragma unroll
                    for (int w = 0; w < W; ++w) R[r][w] = R[r + 1][w];
                int row = py + dbase + dd + P;
#pragma unroll
                for (int w = 0; w < W; ++w)
                    R[P - 1][w] = pc[row * PTW + px + w];
            }
        }
    }
    // zero scores of out-of-image window neighbors (they still enter softmax)
#pragma unroll
    for (int k = 0; k < 28; ++k) {
        int d = dbase + k / 7, dx = k % 7;
        if (!inb(gy + d - 3, gx + dx - 3)) s[k] = 0.f;
    }
    const bool half0 = (m == 0);
    float mx = -3.0e38f;
#pragma unroll
    for (int k = 0; k < 28; ++k) {
        bool own = half0 || (k >= 7);
        mx = own ? fmaxf(mx, s[k]) : mx;
    }
    mx = fmaxf(mx, __shfl_xor(mx, 32));
    float sum = 0.f;
#pragma unroll
    for (int k = 0; k < 28; ++k) {
        bool own = half0 || (k >= 7);
        float e = own ? __expf(s[k] - mx) : 0.f;
        s[k] = e;
        sum += e;
    }
    sum += __shfl_xor(sum, 32);

    float o[5] = {0, 0, 0, 0, 0};
#pragma unroll
    for (int k = 0; k < 28; ++k) {
        int d = dbase + k / 7, dx = k % 7;
        int gr = (py + d) * GTW + px + dx;
#pragma unroll
        for (int c5 = 0; c5 < 5; ++c5)
            o[c5] = fmaf(s[k], sG[c5 * GTH * GTW + gr], o[c5]);
    }
#pragma unroll
    for (int c5 = 0; c5 < 5; ++c5) o[c5] += __shfl_xor(o[c5], 32);

    if (half0) {
        float inv = 1.f / sum;
        int p = gy * 128 + gx;
#pragma unroll
        for (int c5 = 0; c5 < 5; ++c5) oh[c5 * N + p] = o[c5] * inv;
    }
}

__global__ __launch_bounds__(256) void heads_k(float* __restrict__ ws) {
    __shared__ float smem[6052];     // head3 worst case: 1440+3072+1540
    const int t = threadIdx.x;
    const int ty0 = (blockIdx.x >> 3) * 8, tx0 = (blockIdx.x & 7) * 16;
    if (blockIdx.y == 0)
        head_tile<3, 3>(ws + OFF_PHI1, ws + OFF_TH1, ws + OFF_G1, ws + OFF_OH1,
                        smem, ty0, tx0, t);
    else if (blockIdx.y == 1)
        head_tile<5, 1>(ws + OFF_PHI2, ws + OFF_TH2, ws + OFF_G2, ws + OFF_OH2,
                        smem, ty0, tx0, t);
    else
        head_tile<8, 3>(ws + OFF_PHI3, ws + OFF_TH3, ws + OFF_G3, ws + OFF_OH3,
                        smem, ty0, tx0, t);
}

// ---------------------------------------------------------------------------
// K3: assemble, grid (64, 5).
//   y=0: x[0..5) = mlp combine of heads; x[37..42) = conv(pan,w_respan)
//   y=1..4: x[5+8(y-1) .. 5+8y) = conv(u, w_resu) slice
// ---------------------------------------------------------------------------
__global__ __launch_bounds__(256) void assemble_k(
    const float* __restrict__ u, const float* __restrict__ pan,
    const float* __restrict__ wres, const float* __restrict__ wrp,
    const float* __restrict__ mlpw, const float* __restrict__ mlpb,
    float* __restrict__ ws) {
    const int p = blockIdx.x * 256 + threadIdx.x;
    const int y = p >> 7, x = p & 127;
    float* xb = ws + OFF_X;

    if (blockIdx.y == 0) {
        const float w0 = mlpw[0], w1 = mlpw[1], w2 = mlpw[2];
        const float bb = mlpb[0];
#pragma unroll
        for (int c = 0; c < 5; ++c) {
            xb[c * N + p] = ws[OFF_OH1 + c * N + p] * w0 +
                            ws[OFF_OH2 + c * N + p] * w1 +
                            ws[OFF_OH3 + c * N + p] * w2 + bb;
        }
        float a5[5] = {0, 0, 0, 0, 0};
#pragma unroll
        for (int i = 0; i < 3; ++i) {
            int yy = y + i - 1;
#pragma unroll
            for (int j = 0; j < 3; ++j) {
                int xx = x + j - 1;
                float v = inb(yy, xx) ? pan[yy * 128 + xx] : 0.f;
#pragma unroll
                for (int o = 0; o < 5; ++o)
                    a5[o] = fmaf(v, wrp[o * 9 + i * 3 + j], a5[o]);
            }
        }
#pragma unroll
        for (int o = 0; o < 5; ++o) xb[(37 + o) * N + p] = a5[o];
    } else {
        const int ob = (blockIdx.y - 1) * 8;   // resu out-channel base
        float acc[8] = {0, 0, 0, 0, 0, 0, 0, 0};
        for (int ic = 0; ic < 8; ++ic) {
#pragma unroll
            for (int i = 0; i < 3; ++i) {
                int yy = y + i - 1;
#pragma unroll
                for (int j = 0; j < 3; ++j) {
                    int xx = x + j - 1;
                    float v = inb(yy, xx) ? u[ic * N + yy * 128 + xx] : 0.f;
#pragma unroll
                    for (int o = 0; o < 8; ++o)
                        acc[o] = fmaf(v, wres[((ob + o) * 8 + ic) * 9 + i * 3 + j],
                                      acc[o]);
                }
            }
        }
#pragma unroll
        for (int o = 0; o < 8; ++o) xb[(5 + ob + o) * N + p] = acc[o];
    }
}

// ---------------------------------------------------------------------------
// K4: LDS-tiled 3x3 conv, CIN=42. Tile 16x16 (+halo 1 -> 18x18x42 = 53.2 KB),
// 256 threads = 1 px each, OCG output channels/thread. grid (64, 42/OCG).
// ---------------------------------------------------------------------------
template <int OCG, bool BIAS, bool RELU, bool SKIP>
__global__ __launch_bounds__(256) void conv42_k(const float* __restrict__ in,
                                                const float* __restrict__ wt,
                                                const float* __restrict__ bs,
                                                const float* __restrict__ skip,
                                                float* __restrict__ outp) {
    __shared__ float sm[42 * 324];
    const int t = threadIdx.x;
    const int ty0 = (blockIdx.x >> 3) << 4, tx0 = (blockIdx.x & 7) << 4;
    for (int i = t; i < 42 * 324; i += 256) {
        int c = i / 324, rem = i - c * 324;
        int r = rem / 18, cc = rem - r * 18;
        int gy = ty0 - 1 + r, gx = tx0 - 1 + cc;
        sm[i] = inb(gy, gx) ? in[c * N + gy * 128 + gx] : 0.f;
    }
    __syncthreads();

    const int py = t >> 4, px = t & 15;
    const int ocb = blockIdx.y * OCG;
    float acc[OCG];
#pragma unroll
    for (int i = 0; i < OCG; ++i) acc[i] = 0.f;

    for (int ic = 0; ic < 42; ++ic) {
        const float* sc = sm + ic * 324 + py * 18 + px;
        float v0 = sc[0],  v1 = sc[1],  v2 = sc[2];
        float v3 = sc[18], v4 = sc[19], v5 = sc[20];
        float v6 = sc[36], v7 = sc[37], v8 = sc[38];
#pragma unroll
        for (int oc = 0; oc < OCG; ++oc) {
            const float* w = wt + ((ocb + oc) * 42 + ic) * 9;
            float a = acc[oc];
            a = fmaf(v0, w[0], a); a = fmaf(v1, w[1], a); a = fmaf(v2, w[2], a);
            a = fmaf(v3, w[3], a); a = fmaf(v4, w[4], a); a = fmaf(v5, w[5], a);
            a = fmaf(v6, w[6], a); a = fmaf(v7, w[7], a); a = fmaf(v8, w[8], a);
            acc[oc] = a;
        }
    }
    const int p = (ty0 + py) * 128 + tx0 + px;
#pragma unroll
    for (int oc = 0; oc < OCG; ++oc) {
        float r = acc[oc];
        if (BIAS) r += bs[ocb + oc];
        if (SKIP) r += skip[(ocb + oc) * N + p];
        if (RELU) r = fmaxf(r, 0.f);
        outp[(ocb + oc) * N + p] = r;
    }
}

// ---------------------------------------------------------------------------
extern "C" void kernel_launch(void* const* d_in, const int* in_sizes, int n_in,
                              void* d_out, int out_size, void* d_ws, size_t ws_size,
                              hipStream_t stream) {
    (void)in_sizes; (void)n_in; (void)out_size; (void)ws_size;
    float* ws = (float*)d_ws;
    float* out = (float*)d_out;

    const float* u      = (const float*)d_in[0];
    const float* pan    = (const float*)d_in[1];
    const float* wnlu   = (const float*)d_in[2];
    const float* wnlpan = (const float*)d_in[3];
    const float* gphi   = (const float*)d_in[4];
    const float* gth    = (const float*)d_in[5];
    const float* gg     = (const float*)d_in[6];
    const float* sphi   = (const float*)d_in[7];
    const float* sth    = (const float*)d_in[8];
    const float* sg     = (const float*)d_in[9];
    const float* mphi   = (const float*)d_in[10];
    const float* mth    = (const float*)d_in[11];
    const float* mg     = (const float*)d_in[12];
    const float* mlpw   = (const float*)d_in[13];
    const float* mlpb   = (const float*)d_in[14];
    const float* wres   = (const float*)d_in[15];
    const float* wrp    = (const float*)d_in[16];
    const float* wrecon = (const float*)d_in[17];

    features_k<<<dim3(N / 256, 2), 256, 0, stream>>>(
        u, pan, wnlu, wnlpan, gphi, gth, gg, sphi, sth, sg, mphi, mth, mg, ws);
    heads_k<<<dim3(128, 3), 256, 0, stream>>>(ws);
    assemble_k<<<dim3(N / 256, 5), 256, 0, stream>>>(u, pan, wres, wrp, mlpw,
                                                     mlpb, ws);
    for (int r = 0; r < 3; ++r) {
        const float* w1 = (const float*)d_in[18 + 4 * r];
        const float* b1 = (const float*)d_in[19 + 4 * r];
        const float* w2 = (const float*)d_in[20 + 4 * r];
        const float* b2 = (const float*)d_in[21 + 4 * r];
        conv42_k<3, true, true, false>
            <<<dim3(64, 14), 256, 0, stream>>>(ws + OFF_X, w1, b1, nullptr,
                                               ws + OFF_F);
        conv42_k<3, true, true, true>
            <<<dim3(64, 14), 256, 0, stream>>>(ws + OFF_F, w2, b2, ws + OFF_X,
                                               ws + OFF_X);
    }
    conv42_k<2, false, false, false>
        <<<dim3(64, 4), 256, 0, stream>>>(ws + OFF_X, wrecon, nullptr, nullptr,
                                          out);
}

// Round 4
// 528.251 us; speedup vs baseline: 1.0780x; 1.0780x over previous
//
#include <hip/hip_runtime.h>

// ---------------------------------------------------------------------------
// Res_NL pansharpening network, B=1, H=W=128, f32 in/out.
//   features_k : uf/pf 3x3 convs + nine 1x1 transforms (2 output groups)
//   heads_k    : 3 attention heads, LDS-staged, 2 threads/pixel (k-row split)
//   wprep_k    : transpose conv weights into [g][ic][k][oc] slabs
//   assemble_k : mlp combine + resu/respan convs (5 output groups)
//   conv42_k   : chunked double-buffered LDS 3x3 conv, CIN=42, OCT oc/block
// ---------------------------------------------------------------------------

#define DEV __device__ __forceinline__

constexpr int N = 128 * 128;   // 16384 pixels

// ---- workspace layout (float offsets) -------------------------------------
constexpr int OFF_PHI1 =   0 * N;   // 3 ch
constexpr int OFF_TH1  =   3 * N;   // 3 ch
constexpr int OFF_PHI2 =   6 * N;   // 5 ch
constexpr int OFF_TH2  =  11 * N;   // 5 ch
constexpr int OFF_PHI3 =  16 * N;   // 8 ch
constexpr int OFF_TH3  =  24 * N;   // 8 ch
constexpr int OFF_G1   =  32 * N;   // 5 ch
constexpr int OFF_G2   =  37 * N;   // 5 ch
constexpr int OFF_G3   =  42 * N;   // 5 ch
constexpr int OFF_X    =  47 * N;   // 42 ch
// OH overlap F: OH live only heads->assemble; F first written after assemble.
constexpr int OFF_OH1  =  89 * N;   // 5 ch
constexpr int OFF_OH2  =  94 * N;   // 5 ch
constexpr int OFF_OH3  =  99 * N;   // 5 ch
constexpr int OFF_F    =  89 * N;   // 42 ch (res-block temp)
// Weight slabs overwrite the dead phi/theta region AFTER heads_k has run.
constexpr int OFF_WT   = 0;
constexpr int RB_SLAB  = 15876;     // 6 groups * 42*9*7
constexpr int RC_SLAB  = 3024;     // 2 groups * 42*9*4
constexpr int WT_TOTAL = 6 * RB_SLAB + RC_SLAB;   // 98280 < 16*N (dead region)

DEV bool inb(int y, int x) { return (unsigned)y < 128u && (unsigned)x < 128u; }

// ---------------------------------------------------------------------------
// K1: features. grid (64, 2). Group 0 writes phi2/th2/g1/g2/g3 (uf only);
// group 1 writes phi1/th1 (pf) and phi3/th3 (uf++pf). uf conv duplicated.
// ---------------------------------------------------------------------------
__global__ __launch_bounds__(256) void features_k(
    const float* __restrict__ u, const float* __restrict__ pan,
    const float* __restrict__ wnlu, const float* __restrict__ wnlpan,
    const float* __restrict__ gphi, const float* __restrict__ gth,
    const float* __restrict__ gg, const float* __restrict__ sphi,
    const float* __restrict__ sth, const float* __restrict__ sg,
    const float* __restrict__ mphi, const float* __restrict__ mth,
    const float* __restrict__ mg, float* __restrict__ ws) {
    const int p = blockIdx.x * 256 + threadIdx.x;
    const int y = p >> 7, x = p & 127;

    float uf[5] = {0, 0, 0, 0, 0};
    for (int ic = 0; ic < 8; ++ic) {
#pragma unroll
        for (int i = 0; i < 3; ++i) {
            int yy = y + i - 1;
#pragma unroll
            for (int j = 0; j < 3; ++j) {
                int xx = x + j - 1;
                float v = inb(yy, xx) ? u[ic * N + yy * 128 + xx] : 0.f;
#pragma unroll
                for (int o = 0; o < 5; ++o)
                    uf[o] = fmaf(v, wnlu[(o * 8 + ic) * 9 + i * 3 + j], uf[o]);
            }
        }
    }
    if (blockIdx.y == 0) {
#pragma unroll
        for (int o = 0; o < 5; ++o) {
            float a = 0, b = 0, c1 = 0, c2 = 0, c3 = 0;
#pragma unroll
            for (int i = 0; i < 5; ++i) {
                a  = fmaf(sphi[o * 5 + i], uf[i], a);
                b  = fmaf(sth [o * 5 + i], uf[i], b);
                c1 = fmaf(gg  [o * 5 + i], uf[i], c1);
                c2 = fmaf(sg  [o * 5 + i], uf[i], c2);
                c3 = fmaf(mg  [o * 5 + i], uf[i], c3);
            }
            ws[OFF_PHI2 + o * N + p] = a;
            ws[OFF_TH2  + o * N + p] = b;
            ws[OFF_G1   + o * N + p] = c1;
            ws[OFF_G2   + o * N + p] = c2;
            ws[OFF_G3   + o * N + p] = c3;
        }
    } else {
        float pf[3] = {0, 0, 0};
#pragma unroll
        for (int i = 0; i < 3; ++i) {
            int yy = y + i - 1;
#pragma unroll
            for (int j = 0; j < 3; ++j) {
                int xx = x + j - 1;
                float v = inb(yy, xx) ? pan[yy * 128 + xx] : 0.f;
#pragma unroll
                for (int o = 0; o < 3; ++o)
                    pf[o] = fmaf(v, wnlpan[o * 9 + i * 3 + j], pf[o]);
            }
        }
        float cat[8] = {uf[0], uf[1], uf[2], uf[3], uf[4], pf[0], pf[1], pf[2]};
#pragma unroll
        for (int o = 0; o < 3; ++o) {
            float a = 0, b = 0;
#pragma unroll
            for (int i = 0; i < 3; ++i) {
                a = fmaf(gphi[o * 3 + i], pf[i], a);
                b = fmaf(gth [o * 3 + i], pf[i], b);
            }
            ws[OFF_PHI1 + o * N + p] = a;
            ws[OFF_TH1  + o * N + p] = b;
        }
#pragma unroll
        for (int o = 0; o < 8; ++o) {
            float a = 0, b = 0;
#pragma unroll
            for (int i = 0; i < 8; ++i) {
                a = fmaf(mphi[o * 8 + i], cat[i], a);
                b = fmaf(mth [o * 8 + i], cat[i], b);
            }
            ws[OFF_PHI3 + o * N + p] = a;
            ws[OFF_TH3  + o * N + p] = b;
        }
    }
}

// ---------------------------------------------------------------------------
// K2: attention heads, LDS-staged, tile 16 wide x 8 tall, 256 threads =
// 2 threads per pixel (neighbor-row split), merged via __shfl_xor(.,32).
// ---------------------------------------------------------------------------
template <int C, int P>
DEV void head_tile(const float* __restrict__ phi, const float* __restrict__ theta,
                   const float* __restrict__ g, float* __restrict__ oh,
                   float* __restrict__ smem, int ty0, int tx0, int t) {
    constexpr int PR  = P / 2;
    constexpr int H3  = 3 + PR;          // phi halo
    constexpr int W   = 6 + P;           // phi band width (dx+j range)
    constexpr int TTH = 8 + 2 * PR, TTW = 16 + 2 * PR;
    constexpr int PTH = 8 + 2 * H3, PTW = 16 + 2 * H3;
    constexpr int GTH = 14, GTW = 22;    // g halo 3

    float* sT = smem;
    float* sP = sT + C * TTH * TTW;
    float* sG = sP + C * PTH * PTW;

    for (int i = t; i < C * TTH * TTW; i += 256) {
        int c = i / (TTH * TTW), rem = i % (TTH * TTW);
        int r = rem / TTW, cc = rem % TTW;
        int gy = ty0 - PR + r, gx = tx0 - PR + cc;
        sT[i] = inb(gy, gx) ? theta[c * N + gy * 128 + gx] : 0.f;
    }
    for (int i = t; i < C * PTH * PTW; i += 256) {
        int c = i / (PTH * PTW), rem = i % (PTH * PTW);
        int r = rem / PTW, cc = rem % PTW;
        int gy = ty0 - H3 + r, gx = tx0 - H3 + cc;
        sP[i] = inb(gy, gx) ? phi[c * N + gy * 128 + gx] : 0.f;
    }
    for (int i = t; i < 5 * GTH * GTW; i += 256) {
        int c = i / (GTH * GTW), rem = i % (GTH * GTW);
        int r = rem / GTW, cc = rem % GTW;
        int gy = ty0 - 3 + r, gx = tx0 - 3 + cc;
        sG[i] = inb(gy, gx) ? g[c * N + gy * 128 + gx] : 0.f;
    }
    __syncthreads();

    const int wave = t >> 6, lane = t & 63, m = lane >> 5;
    const int pidx = (lane & 31) | (wave << 5);     // 0..127
    const int py = pidx >> 4, px = pidx & 15;
    const int gy = ty0 + py, gx = tx0 + px;
    const int dbase = m * 3;

    float s[28];
#pragma unroll
    for (int k = 0; k < 28; ++k) s[k] = 0.f;

    for (int c = 0; c < C; ++c) {
        const float* tc = sT + c * TTH * TTW;
        const float* pc = sP + c * PTH * PTW;
        float T[P][P];
#pragma unroll
        for (int i = 0; i < P; ++i)
#pragma unroll
            for (int j = 0; j < P; ++j)
                T[i][j] = tc[(py + i) * TTW + px + j];
        float R[P][W];
#pragma unroll
        for (int r = 0; r < P; ++r)
#pragma unroll
            for (int w = 0; w < W; ++w)
                R[r][w] = pc[(py + dbase + r) * PTW + px + w];
#pragma unroll
        for (int dd = 0; dd < 4; ++dd) {
#pragma unroll
            for (int dx = 0; dx < 7; ++dx) {
                float a = 0.f;
#pragma unroll
                for (int i = 0; i < P; ++i)
#pragma unroll
                    for (int j = 0; j < P; ++j)
                        a = fmaf(T[i][j], R[i][dx + j], a);
                s[dd * 7 + dx] += a;
            }
            if (dd < 3) {
#pragma unroll
                for (int r = 0; r < P - 1; ++r)
#pragma unroll
                    for (int w = 0; w < W; ++w) R[r][w] = R[r + 1][w];
                int row = py + dbase + dd + P;
#pragma unroll
                for (int w = 0; w < W; ++w)
                    R[P - 1][w] = pc[row * PTW + px + w];
            }
        }
    }
#pragma unroll
    for (int k = 0; k < 28; ++k) {
        int d = dbase + k / 7, dx = k % 7;
        if (!inb(gy + d - 3, gx + dx - 3)) s[k] = 0.f;
    }
    const bool half0 = (m == 0);
    float mx = -3.0e38f;
#pragma unroll
    for (int k = 0; k < 28; ++k) {
        bool own = half0 || (k >= 7);
        mx = own ? fmaxf(mx, s[k]) : mx;
    }
    mx = fmaxf(mx, __shfl_xor(mx, 32));
    float sum = 0.f;
#pragma unroll
    for (int k = 0; k < 28; ++k) {
        bool own = half0 || (k >= 7);
        float e = own ? __expf(s[k] - mx) : 0.f;
        s[k] = e;
        sum += e;
    }
    sum += __shfl_xor(sum, 32);

    float o[5] = {0, 0, 0, 0, 0};
#pragma unroll
    for (int k = 0; k < 28; ++k) {
        int d = dbase + k / 7, dx = k % 7;
        int gr = (py + d) * GTW + px + dx;
#pragma unroll
        for (int c5 = 0; c5 < 5; ++c5)
            o[c5] = fmaf(s[k], sG[c5 * GTH * GTW + gr], o[c5]);
    }
#pragma unroll
    for (int c5 = 0; c5 < 5; ++c5) o[c5] += __shfl_xor(o[c5], 32);

    if (half0) {
        float inv = 1.f / sum;
        int p = gy * 128 + gx;
#pragma unroll
        for (int c5 = 0; c5 < 5; ++c5) oh[c5 * N + p] = o[c5] * inv;
    }
}

__global__ __launch_bounds__(256) void heads_k(float* __restrict__ ws) {
    __shared__ float smem[6052];     // head3 worst case: 1440+3072+1540
    const int t = threadIdx.x;
    const int ty0 = (blockIdx.x >> 3) * 8, tx0 = (blockIdx.x & 7) * 16;
    if (blockIdx.y == 0)
        head_tile<3, 3>(ws + OFF_PHI1, ws + OFF_TH1, ws + OFF_G1, ws + OFF_OH1,
                        smem, ty0, tx0, t);
    else if (blockIdx.y == 1)
        head_tile<5, 1>(ws + OFF_PHI2, ws + OFF_TH2, ws + OFF_G2, ws + OFF_OH2,
                        smem, ty0, tx0, t);
    else
        head_tile<8, 3>(ws + OFF_PHI3, ws + OFF_TH3, ws + OFF_G3, ws + OFF_OH3,
                        smem, ty0, tx0, t);
}

// ---------------------------------------------------------------------------
// K2b: weight prep. rb convs -> slab[cv][g][ic][k][oc7]; recon -> [g][ic][k][oc4]
// ---------------------------------------------------------------------------
struct WPtrs { const float* w[7]; };   // rb0w1,rb0w2,rb1w1,rb1w2,rb2w1,rb2w2,recon

__global__ __launch_bounds__(256) void wprep_k(WPtrs wp, float* __restrict__ out) {
    int idx = blockIdx.x * 256 + threadIdx.x;
    if (idx >= WT_TOTAL) return;
    if (idx < 6 * RB_SLAB) {
        int cv = idx / RB_SLAB, e = idx % RB_SLAB;
        int g = e / 2646, r = e % 2646;          // 42*9*7 per group
        int ic = r / 63, rr = r % 63;
        int k = rr / 7, oc = rr % 7;
        out[idx] = wp.w[cv][((g * 7 + oc) * 42 + ic) * 9 + k];
    } else {
        int e = idx - 6 * RB_SLAB;
        int g = e / 1512, r = e % 1512;          // 42*9*4 per group
        int ic = r / 36, rr = r % 36;
        int k = rr / 4, oc = rr % 4;
        out[idx] = wp.w[6][((g * 4 + oc) * 42 + ic) * 9 + k];
    }
}

// ---------------------------------------------------------------------------
// K3: assemble, grid (64, 5).
// ---------------------------------------------------------------------------
__global__ __launch_bounds__(256) void assemble_k(
    const float* __restrict__ u, const float* __restrict__ pan,
    const float* __restrict__ wres, const float* __restrict__ wrp,
    const float* __restrict__ mlpw, const float* __restrict__ mlpb,
    float* __restrict__ ws) {
    const int p = blockIdx.x * 256 + threadIdx.x;
    const int y = p >> 7, x = p & 127;
    float* xb = ws + OFF_X;

    if (blockIdx.y == 0) {
        const float w0 = mlpw[0], w1 = mlpw[1], w2 = mlpw[2];
        const float bb = mlpb[0];
#pragma unroll
        for (int c = 0; c < 5; ++c) {
            xb[c * N + p] = ws[OFF_OH1 + c * N + p] * w0 +
                            ws[OFF_OH2 + c * N + p] * w1 +
                            ws[OFF_OH3 + c * N + p] * w2 + bb;
        }
        float a5[5] = {0, 0, 0, 0, 0};
#pragma unroll
        for (int i = 0; i < 3; ++i) {
            int yy = y + i - 1;
#pragma unroll
            for (int j = 0; j < 3; ++j) {
                int xx = x + j - 1;
                float v = inb(yy, xx) ? pan[yy * 128 + xx] : 0.f;
#pragma unroll
                for (int o = 0; o < 5; ++o)
                    a5[o] = fmaf(v, wrp[o * 9 + i * 3 + j], a5[o]);
            }
        }
#pragma unroll
        for (int o = 0; o < 5; ++o) xb[(37 + o) * N + p] = a5[o];
    } else {
        const int ob = (blockIdx.y - 1) * 8;
        float acc[8] = {0, 0, 0, 0, 0, 0, 0, 0};
        for (int ic = 0; ic < 8; ++ic) {
#pragma unroll
            for (int i = 0; i < 3; ++i) {
                int yy = y + i - 1;
#pragma unroll
                for (int j = 0; j < 3; ++j) {
                    int xx = x + j - 1;
                    float v = inb(yy, xx) ? u[ic * N + yy * 128 + xx] : 0.f;
#pragma unroll
                    for (int o = 0; o < 8; ++o)
                        acc[o] = fmaf(v, wres[((ob + o) * 8 + ic) * 9 + i * 3 + j],
                                      acc[o]);
                }
            }
        }
#pragma unroll
        for (int o = 0; o < 8; ++o) xb[(5 + ob + o) * N + p] = acc[o];
    }
}

// ---------------------------------------------------------------------------
// K4: chunked double-buffered LDS 3x3 conv, CIN=42.
// Tile 16x16 px, OCT ocs/block. ic staged in 6 chunks of 7, LDS row stride 19
// (odd -> no 4-way bank conflicts), global prefetch of chunk c+1 overlaps
// FMAs of chunk c. Weights from pre-transposed slab: 63 (OCT=7) contiguous
// floats per ic -> s_load_dwordx16 bursts (block-uniform).
// ---------------------------------------------------------------------------
constexpr int CSTR = 19;                 // LDS row stride
constexpr int CICS = 342;                // 18*19 per ic
constexpr int CBUF = 7 * CICS;           // 2394 floats per chunk buffer

template <int OCT, bool BIAS, bool RELU, bool SKIP>
__global__ __launch_bounds__(256) void conv42_k(const float* __restrict__ in,
                                                const float* __restrict__ wslab,
                                                const float* __restrict__ bs,
                                                const float* __restrict__ skip,
                                                float* __restrict__ outp) {
    __shared__ float sm[2 * CBUF];       // 19.2 KB
    const int t = threadIdx.x;
    const int ty0 = (blockIdx.x >> 3) << 4, tx0 = (blockIdx.x & 7) << 4;
    const int g = blockIdx.y;
    const float* __restrict__ wg = wslab + g * (42 * 9 * OCT);

    // staging offsets are chunk-invariant: precompute once
    int ldsoff[9], goff[9];
    bool gval[9], sval[9];
#pragma unroll
    for (int it = 0; it < 9; ++it) {
        int i = it * 256 + t;
        int ic = i / 324, rem = i - ic * 324;
        int r = rem / 18, c = rem - r * 18;
        int gy = ty0 - 1 + r, gx = tx0 - 1 + c;
        sval[it] = i < 2268;             // 7*324
        gval[it] = sval[it] && inb(gy, gx);
        ldsoff[it] = ic * CICS + r * CSTR + c;
        goff[it] = ic * N + gy * 128 + gx;
    }

    float rg[9];
#pragma unroll
    for (int it = 0; it < 9; ++it)
        rg[it] = gval[it] ? in[goff[it]] : 0.f;
#pragma unroll
    for (int it = 0; it < 9; ++it)
        if (sval[it]) sm[ldsoff[it]] = rg[it];
    __syncthreads();

    const int py = t >> 4, px = t & 15;
    float acc[OCT];
#pragma unroll
    for (int i = 0; i < OCT; ++i) acc[i] = 0.f;

    for (int ch = 0; ch < 6; ++ch) {
        if (ch < 5) {
            const float* inn = in + (ch + 1) * 7 * N;
#pragma unroll
            for (int it = 0; it < 9; ++it)
                rg[it] = gval[it] ? inn[goff[it]] : 0.f;
        }
        const float* buf = sm + (ch & 1) * CBUF;
#pragma unroll
        for (int ic = 0; ic < 7; ++ic) {
            const float* sc = buf + ic * CICS + py * CSTR + px;
            float v0 = sc[0],        v1 = sc[1],        v2 = sc[2];
            float v3 = sc[CSTR],     v4 = sc[CSTR + 1], v5 = sc[CSTR + 2];
            float v6 = sc[2 * CSTR], v7 = sc[2 * CSTR + 1], v8 = sc[2 * CSTR + 2];
            const float* w = wg + (ch * 7 + ic) * 9 * OCT;
#pragma unroll
            for (int oc = 0; oc < OCT; ++oc) {
                float a = acc[oc];
                a = fmaf(v0, w[0 * OCT + oc], a);
                a = fmaf(v1, w[1 * OCT + oc], a);
                a = fmaf(v2, w[2 * OCT + oc], a);
                a = fmaf(v3, w[3 * OCT + oc], a);
                a = fmaf(v4, w[4 * OCT + oc], a);
                a = fmaf(v5, w[5 * OCT + oc], a);
                a = fmaf(v6, w[6 * OCT + oc], a);
                a = fmaf(v7, w[7 * OCT + oc], a);
                a = fmaf(v8, w[8 * OCT + oc], a);
                acc[oc] = a;
            }
        }
        if (ch < 5) {
            float* dst = sm + ((ch + 1) & 1) * CBUF;
#pragma unroll
            for (int it = 0; it < 9; ++it)
                if (sval[it]) dst[ldsoff[it]] = rg[it];
        }
        __syncthreads();
    }

    const int p = (ty0 + py) * 128 + tx0 + px;
#pragma unroll
    for (int oc = 0; oc < OCT; ++oc) {
        float r = acc[oc];
        if (BIAS) r += bs[g * OCT + oc];
        if (SKIP) r += skip[(g * OCT + oc) * N + p];
        if (RELU) r = fmaxf(r, 0.f);
        outp[(g * OCT + oc) * N + p] = r;
    }
}

// ---------------------------------------------------------------------------
extern "C" void kernel_launch(void* const* d_in, const int* in_sizes, int n_in,
                              void* d_out, int out_size, void* d_ws, size_t ws_size,
                              hipStream_t stream) {
    (void)in_sizes; (void)n_in; (void)out_size; (void)ws_size;
    float* ws = (float*)d_ws;
    float* out = (float*)d_out;

    const float* u      = (const float*)d_in[0];
    const float* pan    = (const float*)d_in[1];
    const float* wnlu   = (const float*)d_in[2];
    const float* wnlpan = (const float*)d_in[3];
    const float* gphi   = (const float*)d_in[4];
    const float* gth    = (const float*)d_in[5];
    const float* gg     = (const float*)d_in[6];
    const float* sphi   = (const float*)d_in[7];
    const float* sth    = (const float*)d_in[8];
    const float* sg     = (const float*)d_in[9];
    const float* mphi   = (const float*)d_in[10];
    const float* mth    = (const float*)d_in[11];
    const float* mg     = (const float*)d_in[12];
    const float* mlpw   = (const float*)d_in[13];
    const float* mlpb   = (const float*)d_in[14];
    const float* wres   = (const float*)d_in[15];
    const float* wrp    = (const float*)d_in[16];
    const float* wrecon = (const float*)d_in[17];

    features_k<<<dim3(N / 256, 2), 256, 0, stream>>>(
        u, pan, wnlu, wnlpan, gphi, gth, gg, sphi, sth, sg, mphi, mth, mg, ws);
    heads_k<<<dim3(128, 3), 256, 0, stream>>>(ws);

    // slabs overwrite dead phi/theta region -> must launch after heads_k
    WPtrs wp;
    wp.w[0] = (const float*)d_in[18]; wp.w[1] = (const float*)d_in[20];
    wp.w[2] = (const float*)d_in[22]; wp.w[3] = (const float*)d_in[24];
    wp.w[4] = (const float*)d_in[26]; wp.w[5] = (const float*)d_in[28];
    wp.w[6] = wrecon;
    wprep_k<<<(WT_TOTAL + 255) / 256, 256, 0, stream>>>(wp, ws + OFF_WT);

    assemble_k<<<dim3(N / 256, 5), 256, 0, stream>>>(u, pan, wres, wrp, mlpw,
                                                     mlpb, ws);
    for (int r = 0; r < 3; ++r) {
        const float* b1 = (const float*)d_in[19 + 4 * r];
        const float* b2 = (const float*)d_in[21 + 4 * r];
        const float* s1 = ws + OFF_WT + (2 * r) * RB_SLAB;
        const float* s2 = ws + OFF_WT + (2 * r + 1) * RB_SLAB;
        conv42_k<7, true, true, false>
            <<<dim3(64, 6), 256, 0, stream>>>(ws + OFF_X, s1, b1, nullptr,
                                              ws + OFF_F);
        conv42_k<7, true, true, true>
            <<<dim3(64, 6), 256, 0, stream>>>(ws + OFF_F, s2, b2, ws + OFF_X,
                                              ws + OFF_X);
    }
    conv42_k<4, false, false, false>
        <<<dim3(64, 2), 256, 0, stream>>>(ws + OFF_X, ws + OFF_WT + 6 * RB_SLAB,
                                          nullptr, nullptr, out);
}

// Round 5
// 465.117 us; speedup vs baseline: 1.2243x; 1.1357x over previous
//
#include <hip/hip_runtime.h>

// ---------------------------------------------------------------------------
// Res_NL pansharpening network, B=1, H=W=128, f32 in/out.
//   features_k : uf/pf 3x3 convs + nine 1x1 transforms (2 output groups)
//   heads_k    : 3 attention heads, LDS-staged, 2 threads/pixel (k-row split)
//   wprep_k    : transpose conv weights into [g][ic][k][oc] slabs + zero page
//   assemble_k : mlp combine + resu/respan convs (5 output groups)
//   conv42_k   : direct-global 3x3 conv, 4px/thread via float4, OCT oc/block,
//                zero-page pointer redirect for boundaries, no LDS.
// ---------------------------------------------------------------------------

#define DEV __device__ __forceinline__

constexpr int N = 128 * 128;   // 16384 pixels

// ---- workspace layout (float offsets) -------------------------------------
constexpr int OFF_PHI1 =   0 * N;   // 3 ch
constexpr int OFF_TH1  =   3 * N;   // 3 ch
constexpr int OFF_PHI2 =   6 * N;   // 5 ch
constexpr int OFF_TH2  =  11 * N;   // 5 ch
constexpr int OFF_PHI3 =  16 * N;   // 8 ch
constexpr int OFF_TH3  =  24 * N;   // 8 ch
constexpr int OFF_G1   =  32 * N;   // 5 ch
constexpr int OFF_G2   =  37 * N;   // 5 ch
constexpr int OFF_G3   =  42 * N;   // 5 ch
constexpr int OFF_X    =  47 * N;   // 42 ch
// OH overlap F: OH live only heads->assemble; F first written after assemble.
constexpr int OFF_OH1  =  89 * N;   // 5 ch
constexpr int OFF_OH2  =  94 * N;   // 5 ch
constexpr int OFF_OH3  =  99 * N;   // 5 ch
constexpr int OFF_F    =  89 * N;   // 42 ch (res-block temp)
// Weight slabs overwrite dead phi/theta region AFTER heads_k has run.
constexpr int OFF_WT   = 0;
constexpr int RB_SLAB  = 15876;     // 14 groups * 42*9*3
constexpr int RC_SLAB  = 3024;      // 4 groups * 42*9*2
constexpr int WT_TOTAL = 6 * RB_SLAB + RC_SLAB;   // 98280 <= 6*N
constexpr int OFF_ZERO = 6 * N;     // 8-float zero page (dead after heads_k)

DEV bool inb(int y, int x) { return (unsigned)y < 128u && (unsigned)x < 128u; }

// ---------------------------------------------------------------------------
// K1: features. grid (64, 2). Group 0 writes phi2/th2/g1/g2/g3 (uf only);
// group 1 writes phi1/th1 (pf) and phi3/th3 (uf++pf). uf conv duplicated.
// ---------------------------------------------------------------------------
__global__ __launch_bounds__(256) void features_k(
    const float* __restrict__ u, const float* __restrict__ pan,
    const float* __restrict__ wnlu, const float* __restrict__ wnlpan,
    const float* __restrict__ gphi, const float* __restrict__ gth,
    const float* __restrict__ gg, const float* __restrict__ sphi,
    const float* __restrict__ sth, const float* __restrict__ sg,
    const float* __restrict__ mphi, const float* __restrict__ mth,
    const float* __restrict__ mg, float* __restrict__ ws) {
    const int p = blockIdx.x * 256 + threadIdx.x;
    const int y = p >> 7, x = p & 127;

    float uf[5] = {0, 0, 0, 0, 0};
    for (int ic = 0; ic < 8; ++ic) {
#pragma unroll
        for (int i = 0; i < 3; ++i) {
            int yy = y + i - 1;
#pragma unroll
            for (int j = 0; j < 3; ++j) {
                int xx = x + j - 1;
                float v = inb(yy, xx) ? u[ic * N + yy * 128 + xx] : 0.f;
#pragma unroll
                for (int o = 0; o < 5; ++o)
                    uf[o] = fmaf(v, wnlu[(o * 8 + ic) * 9 + i * 3 + j], uf[o]);
            }
        }
    }
    if (blockIdx.y == 0) {
#pragma unroll
        for (int o = 0; o < 5; ++o) {
            float a = 0, b = 0, c1 = 0, c2 = 0, c3 = 0;
#pragma unroll
            for (int i = 0; i < 5; ++i) {
                a  = fmaf(sphi[o * 5 + i], uf[i], a);
                b  = fmaf(sth [o * 5 + i], uf[i], b);
                c1 = fmaf(gg  [o * 5 + i], uf[i], c1);
                c2 = fmaf(sg  [o * 5 + i], uf[i], c2);
                c3 = fmaf(mg  [o * 5 + i], uf[i], c3);
            }
            ws[OFF_PHI2 + o * N + p] = a;
            ws[OFF_TH2  + o * N + p] = b;
            ws[OFF_G1   + o * N + p] = c1;
            ws[OFF_G2   + o * N + p] = c2;
            ws[OFF_G3   + o * N + p] = c3;
        }
    } else {
        float pf[3] = {0, 0, 0};
#pragma unroll
        for (int i = 0; i < 3; ++i) {
            int yy = y + i - 1;
#pragma unroll
            for (int j = 0; j < 3; ++j) {
                int xx = x + j - 1;
                float v = inb(yy, xx) ? pan[yy * 128 + xx] : 0.f;
#pragma unroll
                for (int o = 0; o < 3; ++o)
                    pf[o] = fmaf(v, wnlpan[o * 9 + i * 3 + j], pf[o]);
            }
        }
        float cat[8] = {uf[0], uf[1], uf[2], uf[3], uf[4], pf[0], pf[1], pf[2]};
#pragma unroll
        for (int o = 0; o < 3; ++o) {
            float a = 0, b = 0;
#pragma unroll
            for (int i = 0; i < 3; ++i) {
                a = fmaf(gphi[o * 3 + i], pf[i], a);
                b = fmaf(gth [o * 3 + i], pf[i], b);
            }
            ws[OFF_PHI1 + o * N + p] = a;
            ws[OFF_TH1  + o * N + p] = b;
        }
#pragma unroll
        for (int o = 0; o < 8; ++o) {
            float a = 0, b = 0;
#pragma unroll
            for (int i = 0; i < 8; ++i) {
                a = fmaf(mphi[o * 8 + i], cat[i], a);
                b = fmaf(mth [o * 8 + i], cat[i], b);
            }
            ws[OFF_PHI3 + o * N + p] = a;
            ws[OFF_TH3  + o * N + p] = b;
        }
    }
}

// ---------------------------------------------------------------------------
// K2: attention heads, LDS-staged, tile 16 wide x 8 tall, 256 threads =
// 2 threads per pixel (neighbor-row split), merged via __shfl_xor(.,32).
// ---------------------------------------------------------------------------
template <int C, int P>
DEV void head_tile(const float* __restrict__ phi, const float* __restrict__ theta,
                   const float* __restrict__ g, float* __restrict__ oh,
                   float* __restrict__ smem, int ty0, int tx0, int t) {
    constexpr int PR  = P / 2;
    constexpr int H3  = 3 + PR;          // phi halo
    constexpr int W   = 6 + P;           // phi band width (dx+j range)
    constexpr int TTH = 8 + 2 * PR, TTW = 16 + 2 * PR;
    constexpr int PTH = 8 + 2 * H3, PTW = 16 + 2 * H3;
    constexpr int GTH = 14, GTW = 22;    // g halo 3

    float* sT = smem;
    float* sP = sT + C * TTH * TTW;
    float* sG = sP + C * PTH * PTW;

    for (int i = t; i < C * TTH * TTW; i += 256) {
        int c = i / (TTH * TTW), rem = i % (TTH * TTW);
        int r = rem / TTW, cc = rem % TTW;
        int gy = ty0 - PR + r, gx = tx0 - PR + cc;
        sT[i] = inb(gy, gx) ? theta[c * N + gy * 128 + gx] : 0.f;
    }
    for (int i = t; i < C * PTH * PTW; i += 256) {
        int c = i / (PTH * PTW), rem = i % (PTH * PTW);
        int r = rem / PTW, cc = rem % PTW;
        int gy = ty0 - H3 + r, gx = tx0 - H3 + cc;
        sP[i] = inb(gy, gx) ? phi[c * N + gy * 128 + gx] : 0.f;
    }
    for (int i = t; i < 5 * GTH * GTW; i += 256) {
        int c = i / (GTH * GTW), rem = i % (GTH * GTW);
        int r = rem / GTW, cc = rem % GTW;
        int gy = ty0 - 3 + r, gx = tx0 - 3 + cc;
        sG[i] = inb(gy, gx) ? g[c * N + gy * 128 + gx] : 0.f;
    }
    __syncthreads();

    const int wave = t >> 6, lane = t & 63, m = lane >> 5;
    const int pidx = (lane & 31) | (wave << 5);     // 0..127
    const int py = pidx >> 4, px = pidx & 15;
    const int gy = ty0 + py, gx = tx0 + px;
    const int dbase = m * 3;

    float s[28];
#pragma unroll
    for (int k = 0; k < 28; ++k) s[k] = 0.f;

    for (int c = 0; c < C; ++c) {
        const float* tc = sT + c * TTH * TTW;
        const float* pc = sP + c * PTH * PTW;
        float T[P][P];
#pragma unroll
        for (int i = 0; i < P; ++i)
#pragma unroll
            for (int j = 0; j < P; ++j)
                T[i][j] = tc[(py + i) * TTW + px + j];
        float R[P][W];
#pragma unroll
        for (int r = 0; r < P; ++r)
#pragma unroll
            for (int w = 0; w < W; ++w)
                R[r][w] = pc[(py + dbase + r) * PTW + px + w];
#pragma unroll
        for (int dd = 0; dd < 4; ++dd) {
#pragma unroll
            for (int dx = 0; dx < 7; ++dx) {
                float a = 0.f;
#pragma unroll
                for (int i = 0; i < P; ++i)
#pragma unroll
                    for (int j = 0; j < P; ++j)
                        a = fmaf(T[i][j], R[i][dx + j], a);
                s[dd * 7 + dx] += a;
            }
            if (dd < 3) {
#pragma unroll
                for (int r = 0; r < P - 1; ++r)
#pragma unroll
                    for (int w = 0; w < W; ++w) R[r][w] = R[r + 1][w];
                int row = py + dbase + dd + P;
#pragma unroll
                for (int w = 0; w < W; ++w)
                    R[P - 1][w] = pc[row * PTW + px + w];
            }
        }
    }
#pragma unroll
    for (int k = 0; k < 28; ++k) {
        int d = dbase + k / 7, dx = k % 7;
        if (!inb(gy + d - 3, gx + dx - 3)) s[k] = 0.f;
    }
    const bool half0 = (m == 0);
    float mx = -3.0e38f;
#pragma unroll
    for (int k = 0; k < 28; ++k) {
        bool own = half0 || (k >= 7);
        mx = own ? fmaxf(mx, s[k]) : mx;
    }
    mx = fmaxf(mx, __shfl_xor(mx, 32));
    float sum = 0.f;
#pragma unroll
    for (int k = 0; k < 28; ++k) {
        bool own = half0 || (k >= 7);
        float e = own ? __expf(s[k] - mx) : 0.f;
        s[k] = e;
        sum += e;
    }
    sum += __shfl_xor(sum, 32);

    float o[5] = {0, 0, 0, 0, 0};
#pragma unroll
    for (int k = 0; k < 28; ++k) {
        int d = dbase + k / 7, dx = k % 7;
        int gr = (py + d) * GTW + px + dx;
#pragma unroll
        for (int c5 = 0; c5 < 5; ++c5)
            o[c5] = fmaf(s[k], sG[c5 * GTH * GTW + gr], o[c5]);
    }
#pragma unroll
    for (int c5 = 0; c5 < 5; ++c5) o[c5] += __shfl_xor(o[c5], 32);

    if (half0) {
        float inv = 1.f / sum;
        int p = gy * 128 + gx;
#pragma unroll
        for (int c5 = 0; c5 < 5; ++c5) oh[c5 * N + p] = o[c5] * inv;
    }
}

__global__ __launch_bounds__(256) void heads_k(float* __restrict__ ws) {
    __shared__ float smem[6052];     // head3 worst case: 1440+3072+1540
    const int t = threadIdx.x;
    const int ty0 = (blockIdx.x >> 3) * 8, tx0 = (blockIdx.x & 7) * 16;
    if (blockIdx.y == 0)
        head_tile<3, 3>(ws + OFF_PHI1, ws + OFF_TH1, ws + OFF_G1, ws + OFF_OH1,
                        smem, ty0, tx0, t);
    else if (blockIdx.y == 1)
        head_tile<5, 1>(ws + OFF_PHI2, ws + OFF_TH2, ws + OFF_G2, ws + OFF_OH2,
                        smem, ty0, tx0, t);
    else
        head_tile<8, 3>(ws + OFF_PHI3, ws + OFF_TH3, ws + OFF_G3, ws + OFF_OH3,
                        smem, ty0, tx0, t);
}

// ---------------------------------------------------------------------------
// K2b: weight prep. rb convs -> slab[cv][g14][ic][k][oc3];
// recon -> [g4][ic][k][oc2]. Also zeroes the 8-float zero page.
// ---------------------------------------------------------------------------
struct WPtrs { const float* w[7]; };   // rb0w1,rb0w2,rb1w1,rb1w2,rb2w1,rb2w2,recon

__global__ __launch_bounds__(256) void wprep_k(WPtrs wp, float* __restrict__ ws) {
    int idx = blockIdx.x * 256 + threadIdx.x;
    if (idx < 8) ws[OFF_ZERO + idx] = 0.f;
    if (idx >= WT_TOTAL) return;
    float* out = ws + OFF_WT;
    if (idx < 6 * RB_SLAB) {
        int cv = idx / RB_SLAB, e = idx % RB_SLAB;
        int g = e / 1134, r = e % 1134;          // 42*9*3 per group
        int ic = r / 27, rr = r % 27;
        int k = rr / 3, oc = rr % 3;
        out[idx] = wp.w[cv][((g * 3 + oc) * 42 + ic) * 9 + k];
    } else {
        int e = idx - 6 * RB_SLAB;
        int g = e / 756, r = e % 756;            // 42*9*2 per group
        int ic = r / 18, rr = r % 18;
        int k = rr / 2, oc = rr % 2;
        out[idx] = wp.w[6][((g * 2 + oc) * 42 + ic) * 9 + k];
    }
}

// ---------------------------------------------------------------------------
// K3: assemble, grid (64, 5).
// ---------------------------------------------------------------------------
__global__ __launch_bounds__(256) void assemble_k(
    const float* __restrict__ u, const float* __restrict__ pan,
    const float* __restrict__ wres, const float* __restrict__ wrp,
    const float* __restrict__ mlpw, const float* __restrict__ mlpb,
    float* __restrict__ ws) {
    const int p = blockIdx.x * 256 + threadIdx.x;
    const int y = p >> 7, x = p & 127;
    float* xb = ws + OFF_X;

    if (blockIdx.y == 0) {
        const float w0 = mlpw[0], w1 = mlpw[1], w2 = mlpw[2];
        const float bb = mlpb[0];
#pragma unroll
        for (int c = 0; c < 5; ++c) {
            xb[c * N + p] = ws[OFF_OH1 + c * N + p] * w0 +
                            ws[OFF_OH2 + c * N + p] * w1 +
                            ws[OFF_OH3 + c * N + p] * w2 + bb;
        }
        float a5[5] = {0, 0, 0, 0, 0};
#pragma unroll
        for (int i = 0; i < 3; ++i) {
            int yy = y + i - 1;
#pragma unroll
            for (int j = 0; j < 3; ++j) {
                int xx = x + j - 1;
                float v = inb(yy, xx) ? pan[yy * 128 + xx] : 0.f;
#pragma unroll
                for (int o = 0; o < 5; ++o)
                    a5[o] = fmaf(v, wrp[o * 9 + i * 3 + j], a5[o]);
            }
        }
#pragma unroll
        for (int o = 0; o < 5; ++o) xb[(37 + o) * N + p] = a5[o];
    } else {
        const int ob = (blockIdx.y - 1) * 8;
        float acc[8] = {0, 0, 0, 0, 0, 0, 0, 0};
        for (int ic = 0; ic < 8; ++ic) {
#pragma unroll
            for (int i = 0; i < 3; ++i) {
                int yy = y + i - 1;
#pragma unroll
                for (int j = 0; j < 3; ++j) {
                    int xx = x + j - 1;
                    float v = inb(yy, xx) ? u[ic * N + yy * 128 + xx] : 0.f;
#pragma unroll
                    for (int o = 0; o < 8; ++o)
                        acc[o] = fmaf(v, wres[((ob + o) * 8 + ic) * 9 + i * 3 + j],
                                      acc[o]);
                }
            }
        }
#pragma unroll
        for (int o = 0; o < 8; ++o) xb[(5 + ob + o) * N + p] = acc[o];
    }
}

// ---------------------------------------------------------------------------
// K4: direct-global 3x3 conv, CIN=42, no LDS. 64-thread blocks, 4 px/thread
// along x. Per ic per row: dword(x0-1) + float4(x0, 16B-aligned) + dword(x0+4).
// Boundary handling via zero-page pointer redirect (ic-stride 0).
// Pixels travel on vmcnt; weights on lgkmcnt (s_load) -> independent counters.
// grid (64, 42/OCT).
// ---------------------------------------------------------------------------
template <int OCT, bool BIAS, bool RELU, bool SKIP>
__global__ __launch_bounds__(64) void conv42_k(const float* __restrict__ in,
                                               const float* __restrict__ wslab,
                                               const float* __restrict__ bs,
                                               const float* __restrict__ skip,
                                               float* __restrict__ outp,
                                               const float* __restrict__ zrow) {
    const int t = threadIdx.x;
    const int tilex = blockIdx.x & 3, tiley = blockIdx.x >> 2;
    const int x0 = tilex * 32 + (t & 7) * 4;
    const int y  = tiley * 8 + (t >> 3);
    const int g  = blockIdx.y;
    const float* __restrict__ wg = wslab + g * (42 * 9 * OCT);

    const float* aL[3]; const float* aC[3]; const float* aR[3];
    int sL[3], sC[3], sR[3];
#pragma unroll
    for (int r = 0; r < 3; ++r) {
        int yy = y + r - 1;
        bool rok = (unsigned)yy < 128u;
        const float* row = in + yy * 128;
        if (rok && x0 > 0)       { aL[r] = row + x0 - 1; sL[r] = N; }
        else                     { aL[r] = zrow;         sL[r] = 0; }
        if (rok)                 { aC[r] = row + x0;     sC[r] = N; }
        else                     { aC[r] = zrow;         sC[r] = 0; }
        if (rok && x0 + 4 < 128) { aR[r] = row + x0 + 4; sR[r] = N; }
        else                     { aR[r] = zrow;         sR[r] = 0; }
    }

    float acc[4][OCT];
#pragma unroll
    for (int i = 0; i < 4; ++i)
#pragma unroll
        for (int oc = 0; oc < OCT; ++oc) acc[i][oc] = 0.f;

#pragma unroll 2
    for (int ic = 0; ic < 42; ++ic) {
        const float* w = wg + ic * 9 * OCT;
        float  vL[3], vR[3];
        float4 C[3];
#pragma unroll
        for (int r = 0; r < 3; ++r) {
            vL[r] = *aL[r];
            C[r]  = *(const float4*)aC[r];
            vR[r] = *aR[r];
            aL[r] += sL[r]; aC[r] += sC[r]; aR[r] += sR[r];
        }
#pragma unroll
        for (int r = 0; r < 3; ++r) {
            float v[6] = {vL[r], C[r].x, C[r].y, C[r].z, C[r].w, vR[r]};
#pragma unroll
            for (int j = 0; j < 3; ++j) {
#pragma unroll
                for (int oc = 0; oc < OCT; ++oc) {
                    float wv = w[(r * 3 + j) * OCT + oc];
#pragma unroll
                    for (int i = 0; i < 4; ++i)
                        acc[i][oc] = fmaf(v[i + j], wv, acc[i][oc]);
                }
            }
        }
    }

    const int p = y * 128 + x0;
#pragma unroll
    for (int oc = 0; oc < OCT; ++oc) {
        float4 res;
        float* rp = (float*)&res;
#pragma unroll
        for (int i = 0; i < 4; ++i) {
            float v = acc[i][oc];
            if (BIAS) v += bs[g * OCT + oc];
            rp[i] = v;
        }
        if (SKIP) {
            float4 sk = *(const float4*)(skip + (g * OCT + oc) * N + p);
            res.x += sk.x; res.y += sk.y; res.z += sk.z; res.w += sk.w;
        }
        if (RELU) {
            res.x = fmaxf(res.x, 0.f); res.y = fmaxf(res.y, 0.f);
            res.z = fmaxf(res.z, 0.f); res.w = fmaxf(res.w, 0.f);
        }
        *(float4*)(outp + (g * OCT + oc) * N + p) = res;
    }
}

// ---------------------------------------------------------------------------
extern "C" void kernel_launch(void* const* d_in, const int* in_sizes, int n_in,
                              void* d_out, int out_size, void* d_ws, size_t ws_size,
                              hipStream_t stream) {
    (void)in_sizes; (void)n_in; (void)out_size; (void)ws_size;
    float* ws = (float*)d_ws;
    float* out = (float*)d_out;

    const float* u      = (const float*)d_in[0];
    const float* pan    = (const float*)d_in[1];
    const float* wnlu   = (const float*)d_in[2];
    const float* wnlpan = (const float*)d_in[3];
    const float* gphi   = (const float*)d_in[4];
    const float* gth    = (const float*)d_in[5];
    const float* gg     = (const float*)d_in[6];
    const float* sphi   = (const float*)d_in[7];
    const float* sth    = (const float*)d_in[8];
    const float* sg     = (const float*)d_in[9];
    const float* mphi   = (const float*)d_in[10];
    const float* mth    = (const float*)d_in[11];
    const float* mg     = (const float*)d_in[12];
    const float* mlpw   = (const float*)d_in[13];
    const float* mlpb   = (const float*)d_in[14];
    const float* wres   = (const float*)d_in[15];
    const float* wrp    = (const float*)d_in[16];
    const float* wrecon = (const float*)d_in[17];

    features_k<<<dim3(N / 256, 2), 256, 0, stream>>>(
        u, pan, wnlu, wnlpan, gphi, gth, gg, sphi, sth, sg, mphi, mth, mg, ws);
    heads_k<<<dim3(128, 3), 256, 0, stream>>>(ws);

    // slabs + zero page overwrite dead phi/theta region -> after heads_k
    WPtrs wp;
    wp.w[0] = (const float*)d_in[18]; wp.w[1] = (const float*)d_in[20];
    wp.w[2] = (const float*)d_in[22]; wp.w[3] = (const float*)d_in[24];
    wp.w[4] = (const float*)d_in[26]; wp.w[5] = (const float*)d_in[28];
    wp.w[6] = wrecon;
    wprep_k<<<(WT_TOTAL + 255) / 256, 256, 0, stream>>>(wp, ws);

    assemble_k<<<dim3(N / 256, 5), 256, 0, stream>>>(u, pan, wres, wrp, mlpw,
                                                     mlpb, ws);
    const float* zrow = ws + OFF_ZERO;
    for (int r = 0; r < 3; ++r) {
        const float* b1 = (const float*)d_in[19 + 4 * r];
        const float* b2 = (const float*)d_in[21 + 4 * r];
        const float* s1 = ws + OFF_WT + (2 * r) * RB_SLAB;
        const float* s2 = ws + OFF_WT + (2 * r + 1) * RB_SLAB;
        conv42_k<3, true, true, false>
            <<<dim3(64, 14), 64, 0, stream>>>(ws + OFF_X, s1, b1, nullptr,
                                              ws + OFF_F, zrow);
        conv42_k<3, true, true, true>
            <<<dim3(64, 14), 64, 0, stream>>>(ws + OFF_F, s2, b2, ws + OFF_X,
                                              ws + OFF_X, zrow);
    }
    conv42_k<2, false, false, false>
        <<<dim3(64, 4), 64, 0, stream>>>(ws + OFF_X, ws + OFF_WT + 6 * RB_SLAB,
                                         nullptr, nullptr, out, zrow);
}

// Round 6
// 328.880 us; speedup vs baseline: 1.7315x; 1.4142x over previous
//
#include <hip/hip_runtime.h>

// ---------------------------------------------------------------------------
// Res_NL pansharpening network, B=1, H=W=128, f32 in/out.
//   features_k : uf/pf 3x3 convs + nine 1x1 transforms (loads hoisted)
//   heads_k    : 3 attention heads, LDS-staged, 2 threads/pixel
//   wprep_k    : transpose conv weights into [g][ic][k][oc] slabs + zero page
//   assemble_k : mlp combine + resu/respan convs (loads hoisted)
//   conv42_k   : direct-global 3x3 conv, 4px/thread, OCT oc/block, zero-page
//                boundary redirect, ic batched 6-at-a-time (load phase -> FMA
//                phase) for memory-level parallelism. No LDS.
// ---------------------------------------------------------------------------

#define DEV __device__ __forceinline__

constexpr int N = 128 * 128;   // 16384 pixels

// ---- workspace layout (float offsets) -------------------------------------
constexpr int OFF_PHI1 =   0 * N;   // 3 ch
constexpr int OFF_TH1  =   3 * N;   // 3 ch
constexpr int OFF_PHI2 =   6 * N;   // 5 ch
constexpr int OFF_TH2  =  11 * N;   // 5 ch
constexpr int OFF_PHI3 =  16 * N;   // 8 ch
constexpr int OFF_TH3  =  24 * N;   // 8 ch
constexpr int OFF_G1   =  32 * N;   // 5 ch
constexpr int OFF_G2   =  37 * N;   // 5 ch
constexpr int OFF_G3   =  42 * N;   // 5 ch
constexpr int OFF_X    =  47 * N;   // 42 ch
// OH overlap F: OH live only heads->assemble; F first written after assemble.
constexpr int OFF_OH1  =  89 * N;   // 5 ch
constexpr int OFF_OH2  =  94 * N;   // 5 ch
constexpr int OFF_OH3  =  99 * N;   // 5 ch
constexpr int OFF_F    =  89 * N;   // 42 ch (res-block temp)
// Weight slabs overwrite dead phi/theta region AFTER heads_k has run.
constexpr int OFF_WT   = 0;
constexpr int RB_SLAB  = 15876;     // 14 groups * 42*9*3
constexpr int RC_SLAB  = 3024;      // 4 groups * 42*9*2
constexpr int WT_TOTAL = 6 * RB_SLAB + RC_SLAB;   // 98280 <= 6*N
constexpr int OFF_ZERO = 6 * N;     // 8-float zero page (dead after heads_k)

DEV bool inb(int y, int x) { return (unsigned)y < 128u && (unsigned)x < 128u; }

// ---------------------------------------------------------------------------
// K1: features. grid (64, 2). Group 0 writes phi2/th2/g1/g2/g3 (uf only);
// group 1 writes phi1/th1 (pf) and phi3/th3 (uf++pf). uf conv duplicated.
// All 72 u-loads hoisted into registers before any FMA (MLP).
// ---------------------------------------------------------------------------
__global__ __launch_bounds__(256, 2) void features_k(
    const float* __restrict__ u, const float* __restrict__ pan,
    const float* __restrict__ wnlu, const float* __restrict__ wnlpan,
    const float* __restrict__ gphi, const float* __restrict__ gth,
    const float* __restrict__ gg, const float* __restrict__ sphi,
    const float* __restrict__ sth, const float* __restrict__ sg,
    const float* __restrict__ mphi, const float* __restrict__ mth,
    const float* __restrict__ mg, float* __restrict__ ws) {
    const int p = blockIdx.x * 256 + threadIdx.x;
    const int y = p >> 7, x = p & 127;

    float uv[8][9];
#pragma unroll
    for (int ic = 0; ic < 8; ++ic)
#pragma unroll
        for (int i = 0; i < 3; ++i)
#pragma unroll
            for (int j = 0; j < 3; ++j) {
                int yy = y + i - 1, xx = x + j - 1;
                uv[ic][i * 3 + j] = inb(yy, xx) ? u[ic * N + yy * 128 + xx] : 0.f;
            }

    float uf[5] = {0, 0, 0, 0, 0};
#pragma unroll
    for (int ic = 0; ic < 8; ++ic)
#pragma unroll
        for (int k = 0; k < 9; ++k)
#pragma unroll
            for (int o = 0; o < 5; ++o)
                uf[o] = fmaf(uv[ic][k], wnlu[(o * 8 + ic) * 9 + k], uf[o]);

    if (blockIdx.y == 0) {
#pragma unroll
        for (int o = 0; o < 5; ++o) {
            float a = 0, b = 0, c1 = 0, c2 = 0, c3 = 0;
#pragma unroll
            for (int i = 0; i < 5; ++i) {
                a  = fmaf(sphi[o * 5 + i], uf[i], a);
                b  = fmaf(sth [o * 5 + i], uf[i], b);
                c1 = fmaf(gg  [o * 5 + i], uf[i], c1);
                c2 = fmaf(sg  [o * 5 + i], uf[i], c2);
                c3 = fmaf(mg  [o * 5 + i], uf[i], c3);
            }
            ws[OFF_PHI2 + o * N + p] = a;
            ws[OFF_TH2  + o * N + p] = b;
            ws[OFF_G1   + o * N + p] = c1;
            ws[OFF_G2   + o * N + p] = c2;
            ws[OFF_G3   + o * N + p] = c3;
        }
    } else {
        float pv[9];
#pragma unroll
        for (int i = 0; i < 3; ++i)
#pragma unroll
            for (int j = 0; j < 3; ++j) {
                int yy = y + i - 1, xx = x + j - 1;
                pv[i * 3 + j] = inb(yy, xx) ? pan[yy * 128 + xx] : 0.f;
            }
        float pf[3] = {0, 0, 0};
#pragma unroll
        for (int k = 0; k < 9; ++k)
#pragma unroll
            for (int o = 0; o < 3; ++o)
                pf[o] = fmaf(pv[k], wnlpan[o * 9 + k], pf[o]);

        float cat[8] = {uf[0], uf[1], uf[2], uf[3], uf[4], pf[0], pf[1], pf[2]};
#pragma unroll
        for (int o = 0; o < 3; ++o) {
            float a = 0, b = 0;
#pragma unroll
            for (int i = 0; i < 3; ++i) {
                a = fmaf(gphi[o * 3 + i], pf[i], a);
                b = fmaf(gth [o * 3 + i], pf[i], b);
            }
            ws[OFF_PHI1 + o * N + p] = a;
            ws[OFF_TH1  + o * N + p] = b;
        }
#pragma unroll
        for (int o = 0; o < 8; ++o) {
            float a = 0, b = 0;
#pragma unroll
            for (int i = 0; i < 8; ++i) {
                a = fmaf(mphi[o * 8 + i], cat[i], a);
                b = fmaf(mth [o * 8 + i], cat[i], b);
            }
            ws[OFF_PHI3 + o * N + p] = a;
            ws[OFF_TH3  + o * N + p] = b;
        }
    }
}

// ---------------------------------------------------------------------------
// K2: attention heads, LDS-staged, tile 16 wide x 8 tall, 256 threads =
// 2 threads per pixel (neighbor-row split), merged via __shfl_xor(.,32).
// ---------------------------------------------------------------------------
template <int C, int P>
DEV void head_tile(const float* __restrict__ phi, const float* __restrict__ theta,
                   const float* __restrict__ g, float* __restrict__ oh,
                   float* __restrict__ smem, int ty0, int tx0, int t) {
    constexpr int PR  = P / 2;
    constexpr int H3  = 3 + PR;          // phi halo
    constexpr int W   = 6 + P;           // phi band width (dx+j range)
    constexpr int TTH = 8 + 2 * PR, TTW = 16 + 2 * PR;
    constexpr int PTH = 8 + 2 * H3, PTW = 16 + 2 * H3;
    constexpr int GTH = 14, GTW = 22;    // g halo 3

    float* sT = smem;
    float* sP = sT + C * TTH * TTW;
    float* sG = sP + C * PTH * PTW;

    for (int i = t; i < C * TTH * TTW; i += 256) {
        int c = i / (TTH * TTW), rem = i % (TTH * TTW);
        int r = rem / TTW, cc = rem % TTW;
        int gy = ty0 - PR + r, gx = tx0 - PR + cc;
        sT[i] = inb(gy, gx) ? theta[c * N + gy * 128 + gx] : 0.f;
    }
    for (int i = t; i < C * PTH * PTW; i += 256) {
        int c = i / (PTH * PTW), rem = i % (PTH * PTW);
        int r = rem / PTW, cc = rem % PTW;
        int gy = ty0 - H3 + r, gx = tx0 - H3 + cc;
        sP[i] = inb(gy, gx) ? phi[c * N + gy * 128 + gx] : 0.f;
    }
    for (int i = t; i < 5 * GTH * GTW; i += 256) {
        int c = i / (GTH * GTW), rem = i % (GTH * GTW);
        int r = rem / GTW, cc = rem % GTW;
        int gy = ty0 - 3 + r, gx = tx0 - 3 + cc;
        sG[i] = inb(gy, gx) ? g[c * N + gy * 128 + gx] : 0.f;
    }
    __syncthreads();

    const int wave = t >> 6, lane = t & 63, m = lane >> 5;
    const int pidx = (lane & 31) | (wave << 5);     // 0..127
    const int py = pidx >> 4, px = pidx & 15;
    const int gy = ty0 + py, gx = tx0 + px;
    const int dbase = m * 3;

    float s[28];
#pragma unroll
    for (int k = 0; k < 28; ++k) s[k] = 0.f;

    for (int c = 0; c < C; ++c) {
        const float* tc = sT + c * TTH * TTW;
        const float* pc = sP + c * PTH * PTW;
        float T[P][P];
#pragma unroll
        for (int i = 0; i < P; ++i)
#pragma unroll
            for (int j = 0; j < P; ++j)
                T[i][j] = tc[(py + i) * TTW + px + j];
        float R[P][W];
#pragma unroll
        for (int r = 0; r < P; ++r)
#pragma unroll
            for (int w = 0; w < W; ++w)
                R[r][w] = pc[(py + dbase + r) * PTW + px + w];
#pragma unroll
        for (int dd = 0; dd < 4; ++dd) {
#pragma unroll
            for (int dx = 0; dx < 7; ++dx) {
                float a = 0.f;
#pragma unroll
                for (int i = 0; i < P; ++i)
#pragma unroll
                    for (int j = 0; j < P; ++j)
                        a = fmaf(T[i][j], R[i][dx + j], a);
                s[dd * 7 + dx] += a;
            }
            if (dd < 3) {
#pragma unroll
                for (int r = 0; r < P - 1; ++r)
#pragma unroll
                    for (int w = 0; w < W; ++w) R[r][w] = R[r + 1][w];
                int row = py + dbase + dd + P;
#pragma unroll
                for (int w = 0; w < W; ++w)
                    R[P - 1][w] = pc[row * PTW + px + w];
            }
        }
    }
#pragma unroll
    for (int k = 0; k < 28; ++k) {
        int d = dbase + k / 7, dx = k % 7;
        if (!inb(gy + d - 3, gx + dx - 3)) s[k] = 0.f;
    }
    const bool half0 = (m == 0);
    float mx = -3.0e38f;
#pragma unroll
    for (int k = 0; k < 28; ++k) {
        bool own = half0 || (k >= 7);
        mx = own ? fmaxf(mx, s[k]) : mx;
    }
    mx = fmaxf(mx, __shfl_xor(mx, 32));
    float sum = 0.f;
#pragma unroll
    for (int k = 0; k < 28; ++k) {
        bool own = half0 || (k >= 7);
        float e = own ? __expf(s[k] - mx) : 0.f;
        s[k] = e;
        sum += e;
    }
    sum += __shfl_xor(sum, 32);

    float o[5] = {0, 0, 0, 0, 0};
#pragma unroll
    for (int k = 0; k < 28; ++k) {
        int d = dbase + k / 7, dx = k % 7;
        int gr = (py + d) * GTW + px + dx;
#pragma unroll
        for (int c5 = 0; c5 < 5; ++c5)
            o[c5] = fmaf(s[k], sG[c5 * GTH * GTW + gr], o[c5]);
    }
#pragma unroll
    for (int c5 = 0; c5 < 5; ++c5) o[c5] += __shfl_xor(o[c5], 32);

    if (half0) {
        float inv = 1.f / sum;
        int p = gy * 128 + gx;
#pragma unroll
        for (int c5 = 0; c5 < 5; ++c5) oh[c5 * N + p] = o[c5] * inv;
    }
}

__global__ __launch_bounds__(256) void heads_k(float* __restrict__ ws) {
    __shared__ float smem[6052];     // head3 worst case: 1440+3072+1540
    const int t = threadIdx.x;
    const int ty0 = (blockIdx.x >> 3) * 8, tx0 = (blockIdx.x & 7) * 16;
    if (blockIdx.y == 0)
        head_tile<3, 3>(ws + OFF_PHI1, ws + OFF_TH1, ws + OFF_G1, ws + OFF_OH1,
                        smem, ty0, tx0, t);
    else if (blockIdx.y == 1)
        head_tile<5, 1>(ws + OFF_PHI2, ws + OFF_TH2, ws + OFF_G2, ws + OFF_OH2,
                        smem, ty0, tx0, t);
    else
        head_tile<8, 3>(ws + OFF_PHI3, ws + OFF_TH3, ws + OFF_G3, ws + OFF_OH3,
                        smem, ty0, tx0, t);
}

// ---------------------------------------------------------------------------
// K2b: weight prep. rb convs -> slab[cv][g14][ic][k][oc3];
// recon -> [g4][ic][k][oc2]. Also zeroes the 8-float zero page.
// ---------------------------------------------------------------------------
struct WPtrs { const float* w[7]; };   // rb0w1,rb0w2,rb1w1,rb1w2,rb2w1,rb2w2,recon

__global__ __launch_bounds__(256) void wprep_k(WPtrs wp, float* __restrict__ ws) {
    int idx = blockIdx.x * 256 + threadIdx.x;
    if (idx < 8) ws[OFF_ZERO + idx] = 0.f;
    if (idx >= WT_TOTAL) return;
    float* out = ws + OFF_WT;
    if (idx < 6 * RB_SLAB) {
        int cv = idx / RB_SLAB, e = idx % RB_SLAB;
        int g = e / 1134, r = e % 1134;          // 42*9*3 per group
        int ic = r / 27, rr = r % 27;
        int k = rr / 3, oc = rr % 3;
        out[idx] = wp.w[cv][((g * 3 + oc) * 42 + ic) * 9 + k];
    } else {
        int e = idx - 6 * RB_SLAB;
        int g = e / 756, r = e % 756;            // 42*9*2 per group
        int ic = r / 18, rr = r % 18;
        int k = rr / 2, oc = rr % 2;
        out[idx] = wp.w[6][((g * 2 + oc) * 42 + ic) * 9 + k];
    }
}

// ---------------------------------------------------------------------------
// K3: assemble, grid (64, 5). u-loads hoisted before FMAs.
// ---------------------------------------------------------------------------
__global__ __launch_bounds__(256, 2) void assemble_k(
    const float* __restrict__ u, const float* __restrict__ pan,
    const float* __restrict__ wres, const float* __restrict__ wrp,
    const float* __restrict__ mlpw, const float* __restrict__ mlpb,
    float* __restrict__ ws) {
    const int p = blockIdx.x * 256 + threadIdx.x;
    const int y = p >> 7, x = p & 127;
    float* xb = ws + OFF_X;

    if (blockIdx.y == 0) {
        const float w0 = mlpw[0], w1 = mlpw[1], w2 = mlpw[2];
        const float bb = mlpb[0];
#pragma unroll
        for (int c = 0; c < 5; ++c) {
            xb[c * N + p] = ws[OFF_OH1 + c * N + p] * w0 +
                            ws[OFF_OH2 + c * N + p] * w1 +
                            ws[OFF_OH3 + c * N + p] * w2 + bb;
        }
        float pv[9];
#pragma unroll
        for (int i = 0; i < 3; ++i)
#pragma unroll
            for (int j = 0; j < 3; ++j) {
                int yy = y + i - 1, xx = x + j - 1;
                pv[i * 3 + j] = inb(yy, xx) ? pan[yy * 128 + xx] : 0.f;
            }
        float a5[5] = {0, 0, 0, 0, 0};
#pragma unroll
        for (int k = 0; k < 9; ++k)
#pragma unroll
            for (int o = 0; o < 5; ++o)
                a5[o] = fmaf(pv[k], wrp[o * 9 + k], a5[o]);
#pragma unroll
        for (int o = 0; o < 5; ++o) xb[(37 + o) * N + p] = a5[o];
    } else {
        const int ob = (blockIdx.y - 1) * 8;
        float uv[8][9];
#pragma unroll
        for (int ic = 0; ic < 8; ++ic)
#pragma unroll
            for (int i = 0; i < 3; ++i)
#pragma unroll
                for (int j = 0; j < 3; ++j) {
                    int yy = y + i - 1, xx = x + j - 1;
                    uv[ic][i * 3 + j] =
                        inb(yy, xx) ? u[ic * N + yy * 128 + xx] : 0.f;
                }
        float acc[8] = {0, 0, 0, 0, 0, 0, 0, 0};
#pragma unroll
        for (int ic = 0; ic < 8; ++ic)
#pragma unroll
            for (int k = 0; k < 9; ++k)
#pragma unroll
                for (int o = 0; o < 8; ++o)
                    acc[o] = fmaf(uv[ic][k], wres[((ob + o) * 8 + ic) * 9 + k],
                                  acc[o]);
#pragma unroll
        for (int o = 0; o < 8; ++o) xb[(5 + ob + o) * N + p] = acc[o];
    }
}

// ---------------------------------------------------------------------------
// K4: direct-global 3x3 conv, CIN=42, no LDS. 64-thread blocks, 4 px/thread.
// ic processed in 7 batches of 6: load phase (54 batched loads -> one vmcnt
// window) then FMA phase (1296 cyc) -- memory-level parallelism inside the
// wave. Boundary handling via zero-page pointer redirect (ic-stride 0).
// grid (64, 42/OCT).
// ---------------------------------------------------------------------------
struct RowV { float l; float4 c; float r; };

template <int OCT, bool BIAS, bool RELU, bool SKIP>
__global__ __launch_bounds__(64, 1) void conv42_k(const float* __restrict__ in,
                                                  const float* __restrict__ wslab,
                                                  const float* __restrict__ bs,
                                                  const float* __restrict__ skip,
                                                  float* __restrict__ outp,
                                                  const float* __restrict__ zrow) {
    const int t = threadIdx.x;
    const int tilex = blockIdx.x & 3, tiley = blockIdx.x >> 2;
    const int x0 = tilex * 32 + (t & 7) * 4;
    const int y  = tiley * 8 + (t >> 3);
    const int g  = blockIdx.y;
    const float* __restrict__ wg = wslab + g * (42 * 9 * OCT);

    const float* aL[3]; const float* aC[3]; const float* aR[3];
    int sL[3], sC[3], sR[3];
#pragma unroll
    for (int r = 0; r < 3; ++r) {
        int yy = y + r - 1;
        bool rok = (unsigned)yy < 128u;
        const float* row = in + yy * 128;
        if (rok && x0 > 0)       { aL[r] = row + x0 - 1; sL[r] = N; }
        else                     { aL[r] = zrow;         sL[r] = 0; }
        if (rok)                 { aC[r] = row + x0;     sC[r] = N; }
        else                     { aC[r] = zrow;         sC[r] = 0; }
        if (rok && x0 + 4 < 128) { aR[r] = row + x0 + 4; sR[r] = N; }
        else                     { aR[r] = zrow;         sR[r] = 0; }
    }

    float acc[4][OCT];
#pragma unroll
    for (int i = 0; i < 4; ++i)
#pragma unroll
        for (int oc = 0; oc < OCT; ++oc) acc[i][oc] = 0.f;

#pragma unroll 1
    for (int bb = 0; bb < 7; ++bb) {
        RowV vals[6][3];
        // ---- load phase: 54 independent loads, one vmcnt window ----
#pragma unroll
        for (int b = 0; b < 6; ++b)
#pragma unroll
            for (int r = 0; r < 3; ++r) {
                vals[b][r].l = *aL[r];
                vals[b][r].c = *(const float4*)aC[r];
                vals[b][r].r = *aR[r];
                aL[r] += sL[r]; aC[r] += sC[r]; aR[r] += sR[r];
            }
        // ---- FMA phase ----
        const float* w = wg + bb * 6 * 9 * OCT;
#pragma unroll
        for (int b = 0; b < 6; ++b)
#pragma unroll
            for (int r = 0; r < 3; ++r) {
                float v[6] = {vals[b][r].l, vals[b][r].c.x, vals[b][r].c.y,
                              vals[b][r].c.z, vals[b][r].c.w, vals[b][r].r};
#pragma unroll
                for (int j = 0; j < 3; ++j)
#pragma unroll
                    for (int oc = 0; oc < OCT; ++oc) {
                        float wv = w[(b * 9 + r * 3 + j) * OCT + oc];
#pragma unroll
                        for (int i = 0; i < 4; ++i)
                            acc[i][oc] = fmaf(v[i + j], wv, acc[i][oc]);
                    }
            }
    }

    const int p = y * 128 + x0;
#pragma unroll
    for (int oc = 0; oc < OCT; ++oc) {
        float4 res;
        float* rp = (float*)&res;
#pragma unroll
        for (int i = 0; i < 4; ++i) {
            float v = acc[i][oc];
            if (BIAS) v += bs[g * OCT + oc];
            rp[i] = v;
        }
        if (SKIP) {
            float4 sk = *(const float4*)(skip + (g * OCT + oc) * N + p);
            res.x += sk.x; res.y += sk.y; res.z += sk.z; res.w += sk.w;
        }
        if (RELU) {
            res.x = fmaxf(res.x, 0.f); res.y = fmaxf(res.y, 0.f);
            res.z = fmaxf(res.z, 0.f); res.w = fmaxf(res.w, 0.f);
        }
        *(float4*)(outp + (g * OCT + oc) * N + p) = res;
    }
}

// ---------------------------------------------------------------------------
extern "C" void kernel_launch(void* const* d_in, const int* in_sizes, int n_in,
                              void* d_out, int out_size, void* d_ws, size_t ws_size,
                              hipStream_t stream) {
    (void)in_sizes; (void)n_in; (void)out_size; (void)ws_size;
    float* ws = (float*)d_ws;
    float* out = (float*)d_out;

    const float* u      = (const float*)d_in[0];
    const float* pan    = (const float*)d_in[1];
    const float* wnlu   = (const float*)d_in[2];
    const float* wnlpan = (const float*)d_in[3];
    const float* gphi   = (const float*)d_in[4];
    const float* gth    = (const float*)d_in[5];
    const float* gg     = (const float*)d_in[6];
    const float* sphi   = (const float*)d_in[7];
    const float* sth    = (const float*)d_in[8];
    const float* sg     = (const float*)d_in[9];
    const float* mphi   = (const float*)d_in[10];
    const float* mth    = (const float*)d_in[11];
    const float* mg     = (const float*)d_in[12];
    const float* mlpw   = (const float*)d_in[13];
    const float* mlpb   = (const float*)d_in[14];
    const float* wres   = (const float*)d_in[15];
    const float* wrp    = (const float*)d_in[16];
    const float* wrecon = (const float*)d_in[17];

    features_k<<<dim3(N / 256, 2), 256, 0, stream>>>(
        u, pan, wnlu, wnlpan, gphi, gth, gg, sphi, sth, sg, mphi, mth, mg, ws);
    heads_k<<<dim3(128, 3), 256, 0, stream>>>(ws);

    // slabs + zero page overwrite dead phi/theta region -> after heads_k
    WPtrs wp;
    wp.w[0] = (const float*)d_in[18]; wp.w[1] = (const float*)d_in[20];
    wp.w[2] = (const float*)d_in[22]; wp.w[3] = (const float*)d_in[24];
    wp.w[4] = (const float*)d_in[26]; wp.w[5] = (const float*)d_in[28];
    wp.w[6] = wrecon;
    wprep_k<<<(WT_TOTAL + 255) / 256, 256, 0, stream>>>(wp, ws);

    assemble_k<<<dim3(N / 256, 5), 256, 0, stream>>>(u, pan, wres, wrp, mlpw,
                                                     mlpb, ws);
    const float* zrow = ws + OFF_ZERO;
    for (int r = 0; r < 3; ++r) {
        const float* b1 = (const float*)d_in[19 + 4 * r];
        const float* b2 = (const float*)d_in[21 + 4 * r];
        const float* s1 = ws + OFF_WT + (2 * r) * RB_SLAB;
        const float* s2 = ws + OFF_WT + (2 * r + 1) * RB_SLAB;
        conv42_k<3, true, true, false>
            <<<dim3(64, 14), 64, 0, stream>>>(ws + OFF_X, s1, b1, nullptr,
                                              ws + OFF_F, zrow);
        conv42_k<3, true, true, true>
            <<<dim3(64, 14), 64, 0, stream>>>(ws + OFF_F, s2, b2, ws + OFF_X,
                                              ws + OFF_X, zrow);
    }
    conv42_k<2, false, false, false>
        <<<dim3(64, 4), 64, 0, stream>>>(ws + OFF_X, ws + OFF_WT + 6 * RB_SLAB,
                                         nullptr, nullptr, out, zrow);
}

// Round 7
// 277.203 us; speedup vs baseline: 2.0543x; 1.1864x over previous
//
#include <hip/hip_runtime.h>

// ---------------------------------------------------------------------------
// Res_NL pansharpening network, B=1, H=W=128, f32 in/out.
//   features_k : uf/pf 3x3 convs + nine 1x1 transforms (loads hoisted)
//   heads_k    : 3 attention heads, LDS-staged, 2 threads/pixel
//   wprep_k    : build bf16 MFMA A-layout weight slabs + B-offset table
//   assemble_k : mlp combine + resu/respan convs; writes x in f32 AND bf16
//   convm_k    : rb/recon convs as implicit GEMM on mfma_f32_16x16x32_bf16
// ---------------------------------------------------------------------------

#define DEV __device__ __forceinline__
typedef float f32x4 __attribute__((ext_vector_type(4)));
typedef __bf16 bf16x8 __attribute__((ext_vector_type(8)));
typedef unsigned short u16;

constexpr int N = 128 * 128;   // 16384 pixels

// ---- workspace layout (float offsets) -------------------------------------
constexpr int OFF_PHI1 =   0 * N;   // 3 ch
constexpr int OFF_TH1  =   3 * N;   // 3 ch
constexpr int OFF_PHI2 =   6 * N;   // 5 ch
constexpr int OFF_TH2  =  11 * N;   // 5 ch
constexpr int OFF_PHI3 =  16 * N;   // 8 ch
constexpr int OFF_TH3  =  24 * N;   // 8 ch
constexpr int OFF_G1   =  32 * N;   // 5 ch
constexpr int OFF_G2   =  37 * N;   // 5 ch
constexpr int OFF_G3   =  42 * N;   // 5 ch
constexpr int OFF_X    =  47 * N;   // 42 ch f32 (skip path)
constexpr int OFF_OH1  =  89 * N;   // 5 ch
constexpr int OFF_OH2  =  94 * N;   // 5 ch
constexpr int OFF_OH3  =  99 * N;   // 5 ch
// bf16 activation buffers + MFMA weight slabs (u16 regions, float offsets)
constexpr int OFF_XB16 = 110 * N;   // u16[42*N]  x in bf16
constexpr int OFF_FB16 = 131 * N;   // u16[42*N]  f in bf16
constexpr int OFF_SLAB = 152 * N;   // u16[116736] A-layout weights
constexpr int OFF_BTAB = 168 * N;   // u16[384]    B offset table
// slab geometry: rb conv cv in [0,6): 3mt*12ks*64lane*8j = 18432 each;
// recon at 110592: 1mt*12*64*8 = 6144. total 116736.
constexpr int SLAB_RB   = 18432;
constexpr int SLAB_RC   = 110592;
constexpr int SLAB_TOT  = 116736;

DEV bool inb(int y, int x) { return (unsigned)y < 128u && (unsigned)x < 128u; }
DEV u16 f2bf(float f) {
    unsigned u = __float_as_uint(f);
    return (u16)((u + 0x7fffu + ((u >> 16) & 1u)) >> 16);
}

// ---------------------------------------------------------------------------
// K1: features. grid (64, 2). Group 0 writes phi2/th2/g1/g2/g3 (uf only);
// group 1 writes phi1/th1 (pf) and phi3/th3 (uf++pf). uf conv duplicated.
// ---------------------------------------------------------------------------
__global__ __launch_bounds__(256, 2) void features_k(
    const float* __restrict__ u, const float* __restrict__ pan,
    const float* __restrict__ wnlu, const float* __restrict__ wnlpan,
    const float* __restrict__ gphi, const float* __restrict__ gth,
    const float* __restrict__ gg, const float* __restrict__ sphi,
    const float* __restrict__ sth, const float* __restrict__ sg,
    const float* __restrict__ mphi, const float* __restrict__ mth,
    const float* __restrict__ mg, float* __restrict__ ws) {
    const int p = blockIdx.x * 256 + threadIdx.x;
    const int y = p >> 7, x = p & 127;

    float uv[8][9];
#pragma unroll
    for (int ic = 0; ic < 8; ++ic)
#pragma unroll
        for (int i = 0; i < 3; ++i)
#pragma unroll
            for (int j = 0; j < 3; ++j) {
                int yy = y + i - 1, xx = x + j - 1;
                uv[ic][i * 3 + j] = inb(yy, xx) ? u[ic * N + yy * 128 + xx] : 0.f;
            }

    float uf[5] = {0, 0, 0, 0, 0};
#pragma unroll
    for (int ic = 0; ic < 8; ++ic)
#pragma unroll
        for (int k = 0; k < 9; ++k)
#pragma unroll
            for (int o = 0; o < 5; ++o)
                uf[o] = fmaf(uv[ic][k], wnlu[(o * 8 + ic) * 9 + k], uf[o]);

    if (blockIdx.y == 0) {
#pragma unroll
        for (int o = 0; o < 5; ++o) {
            float a = 0, b = 0, c1 = 0, c2 = 0, c3 = 0;
#pragma unroll
            for (int i = 0; i < 5; ++i) {
                a  = fmaf(sphi[o * 5 + i], uf[i], a);
                b  = fmaf(sth [o * 5 + i], uf[i], b);
                c1 = fmaf(gg  [o * 5 + i], uf[i], c1);
                c2 = fmaf(sg  [o * 5 + i], uf[i], c2);
                c3 = fmaf(mg  [o * 5 + i], uf[i], c3);
            }
            ws[OFF_PHI2 + o * N + p] = a;
            ws[OFF_TH2  + o * N + p] = b;
            ws[OFF_G1   + o * N + p] = c1;
            ws[OFF_G2   + o * N + p] = c2;
            ws[OFF_G3   + o * N + p] = c3;
        }
    } else {
        float pv[9];
#pragma unroll
        for (int i = 0; i < 3; ++i)
#pragma unroll
            for (int j = 0; j < 3; ++j) {
                int yy = y + i - 1, xx = x + j - 1;
                pv[i * 3 + j] = inb(yy, xx) ? pan[yy * 128 + xx] : 0.f;
            }
        float pf[3] = {0, 0, 0};
#pragma unroll
        for (int k = 0; k < 9; ++k)
#pragma unroll
            for (int o = 0; o < 3; ++o)
                pf[o] = fmaf(pv[k], wnlpan[o * 9 + k], pf[o]);

        float cat[8] = {uf[0], uf[1], uf[2], uf[3], uf[4], pf[0], pf[1], pf[2]};
#pragma unroll
        for (int o = 0; o < 3; ++o) {
            float a = 0, b = 0;
#pragma unroll
            for (int i = 0; i < 3; ++i) {
                a = fmaf(gphi[o * 3 + i], pf[i], a);
                b = fmaf(gth [o * 3 + i], pf[i], b);
            }
            ws[OFF_PHI1 + o * N + p] = a;
            ws[OFF_TH1  + o * N + p] = b;
        }
#pragma unroll
        for (int o = 0; o < 8; ++o) {
            float a = 0, b = 0;
#pragma unroll
            for (int i = 0; i < 8; ++i) {
                a = fmaf(mphi[o * 8 + i], cat[i], a);
                b = fmaf(mth [o * 8 + i], cat[i], b);
            }
            ws[OFF_PHI3 + o * N + p] = a;
            ws[OFF_TH3  + o * N + p] = b;
        }
    }
}

// ---------------------------------------------------------------------------
// K2: attention heads, LDS-staged, tile 16 wide x 8 tall, 256 threads =
// 2 threads per pixel (neighbor-row split), merged via __shfl_xor(.,32).
// ---------------------------------------------------------------------------
template <int C, int P>
DEV void head_tile(const float* __restrict__ phi, const float* __restrict__ theta,
                   const float* __restrict__ g, float* __restrict__ oh,
                   float* __restrict__ smem, int ty0, int tx0, int t) {
    constexpr int PR  = P / 2;
    constexpr int H3  = 3 + PR;
    constexpr int W   = 6 + P;
    constexpr int TTH = 8 + 2 * PR, TTW = 16 + 2 * PR;
    constexpr int PTH = 8 + 2 * H3, PTW = 16 + 2 * H3;
    constexpr int GTH = 14, GTW = 22;

    float* sT = smem;
    float* sP = sT + C * TTH * TTW;
    float* sG = sP + C * PTH * PTW;

    for (int i = t; i < C * TTH * TTW; i += 256) {
        int c = i / (TTH * TTW), rem = i % (TTH * TTW);
        int r = rem / TTW, cc = rem % TTW;
        int gy = ty0 - PR + r, gx = tx0 - PR + cc;
        sT[i] = inb(gy, gx) ? theta[c * N + gy * 128 + gx] : 0.f;
    }
    for (int i = t; i < C * PTH * PTW; i += 256) {
        int c = i / (PTH * PTW), rem = i % (PTH * PTW);
        int r = rem / PTW, cc = rem % PTW;
        int gy = ty0 - H3 + r, gx = tx0 - H3 + cc;
        sP[i] = inb(gy, gx) ? phi[c * N + gy * 128 + gx] : 0.f;
    }
    for (int i = t; i < 5 * GTH * GTW; i += 256) {
        int c = i / (GTH * GTW), rem = i % (GTH * GTW);
        int r = rem / GTW, cc = rem % GTW;
        int gy = ty0 - 3 + r, gx = tx0 - 3 + cc;
        sG[i] = inb(gy, gx) ? g[c * N + gy * 128 + gx] : 0.f;
    }
    __syncthreads();

    const int wave = t >> 6, lane = t & 63, m = lane >> 5;
    const int pidx = (lane & 31) | (wave << 5);
    const int py = pidx >> 4, px = pidx & 15;
    const int gy = ty0 + py, gx = tx0 + px;
    const int dbase = m * 3;

    float s[28];
#pragma unroll
    for (int k = 0; k < 28; ++k) s[k] = 0.f;

    for (int c = 0; c < C; ++c) {
        const float* tc = sT + c * TTH * TTW;
        const float* pc = sP + c * PTH * PTW;
        float T[P][P];
#pragma unroll
        for (int i = 0; i < P; ++i)
#pragma unroll
            for (int j = 0; j < P; ++j)
                T[i][j] = tc[(py + i) * TTW + px + j];
        float R[P][W];
#pragma unroll
        for (int r = 0; r < P; ++r)
#pragma unroll
            for (int w = 0; w < W; ++w)
                R[r][w] = pc[(py + dbase + r) * PTW + px + w];
#pragma unroll
        for (int dd = 0; dd < 4; ++dd) {
#pragma unroll
            for (int dx = 0; dx < 7; ++dx) {
                float a = 0.f;
#pragma unroll
                for (int i = 0; i < P; ++i)
#pragma unroll
                    for (int j = 0; j < P; ++j)
                        a = fmaf(T[i][j], R[i][dx + j], a);
                s[dd * 7 + dx] += a;
            }
            if (dd < 3) {
#pragma unroll
                for (int r = 0; r < P - 1; ++r)
#pragma unroll
                    for (int w = 0; w < W; ++w) R[r][w] = R[r + 1][w];
                int row = py + dbase + dd + P;
#pragma unroll
                for (int w = 0; w < W; ++w)
                    R[P - 1][w] = pc[row * PTW + px + w];
            }
        }
    }
#pragma unroll
    for (int k = 0; k < 28; ++k) {
        int d = dbase + k / 7, dx = k % 7;
        if (!inb(gy + d - 3, gx + dx - 3)) s[k] = 0.f;
    }
    const bool half0 = (m == 0);
    float mx = -3.0e38f;
#pragma unroll
    for (int k = 0; k < 28; ++k) {
        bool own = half0 || (k >= 7);
        mx = own ? fmaxf(mx, s[k]) : mx;
    }
    mx = fmaxf(mx, __shfl_xor(mx, 32));
    float sum = 0.f;
#pragma unroll
    for (int k = 0; k < 28; ++k) {
        bool own = half0 || (k >= 7);
        float e = own ? __expf(s[k] - mx) : 0.f;
        s[k] = e;
        sum += e;
    }
    sum += __shfl_xor(sum, 32);

    float o[5] = {0, 0, 0, 0, 0};
#pragma unroll
    for (int k = 0; k < 28; ++k) {
        int d = dbase + k / 7, dx = k % 7;
        int gr = (py + d) * GTW + px + dx;
#pragma unroll
        for (int c5 = 0; c5 < 5; ++c5)
            o[c5] = fmaf(s[k], sG[c5 * GTH * GTW + gr], o[c5]);
    }
#pragma unroll
    for (int c5 = 0; c5 < 5; ++c5) o[c5] += __shfl_xor(o[c5], 32);

    if (half0) {
        float inv = 1.f / sum;
        int p = gy * 128 + gx;
#pragma unroll
        for (int c5 = 0; c5 < 5; ++c5) oh[c5 * N + p] = o[c5] * inv;
    }
}

__global__ __launch_bounds__(256) void heads_k(float* __restrict__ ws) {
    __shared__ float smem[6052];
    const int t = threadIdx.x;
    const int ty0 = (blockIdx.x >> 3) * 8, tx0 = (blockIdx.x & 7) * 16;
    if (blockIdx.y == 0)
        head_tile<3, 3>(ws + OFF_PHI1, ws + OFF_TH1, ws + OFF_G1, ws + OFF_OH1,
                        smem, ty0, tx0, t);
    else if (blockIdx.y == 1)
        head_tile<5, 1>(ws + OFF_PHI2, ws + OFF_TH2, ws + OFF_G2, ws + OFF_OH2,
                        smem, ty0, tx0, t);
    else
        head_tile<8, 3>(ws + OFF_PHI3, ws + OFF_TH3, ws + OFF_G3, ws + OFF_OH3,
                        smem, ty0, tx0, t);
}

// ---------------------------------------------------------------------------
// K2b: weight prep -> bf16 MFMA A-layout slabs + B offset table.
// A-layout per lane: A[m = lane&15][k = (lane>>4)*8 + j], k = ic*9 + tau.
// Btab[k] = ic*198 + (tau/3)*66 + (tau%3)  (u16 LDS element offset, +n later)
// ---------------------------------------------------------------------------
struct WPtrs { const float* w[7]; };   // rb0w1,rb0w2,rb1w1,rb1w2,rb2w1,rb2w2,recon

__global__ __launch_bounds__(256) void wprep_k(WPtrs wp, u16* __restrict__ slab,
                                               u16* __restrict__ btab) {
    int idx = blockIdx.x * 256 + threadIdx.x;
    if (idx < 384) {
        u16 v = 0;
        if (idx < 378) {
            int ic = idx / 9, tau = idx - ic * 9;
            v = (u16)(ic * 198 + (tau / 3) * 66 + (tau % 3));
        }
        btab[idx] = v;
    }
    int e = idx - 384;
    if (e < 0 || e >= SLAB_TOT) return;
    const float* W;
    int mt, ks, lane, j, ocv;
    if (e < SLAB_RC) {
        int cv = e / SLAB_RB, r = e - cv * SLAB_RB;
        mt = r / 6144; r -= mt * 6144;
        ks = r / 512;  r -= ks * 512;
        lane = r / 8;  j = r - lane * 8;
        W = wp.w[cv]; ocv = 42;
    } else {
        int r = e - SLAB_RC;
        mt = 0;
        ks = r / 512;  r -= ks * 512;
        lane = r / 8;  j = r - lane * 8;
        W = wp.w[6]; ocv = 8;
    }
    int k  = ks * 32 + (lane >> 4) * 8 + j;
    int oc = mt * 16 + (lane & 15);
    u16 v = 0;
    if (k < 378 && oc < ocv) {
        int ic = k / 9, tau = k - ic * 9;
        v = f2bf(W[(oc * 42 + ic) * 9 + tau]);
    }
    slab[e] = v;
}

// ---------------------------------------------------------------------------
// K3: assemble, grid (64, 5). Writes x f32 (skip path) AND bf16 (MFMA input).
// ---------------------------------------------------------------------------
__global__ __launch_bounds__(256, 2) void assemble_k(
    const float* __restrict__ u, const float* __restrict__ pan,
    const float* __restrict__ wres, const float* __restrict__ wrp,
    const float* __restrict__ mlpw, const float* __restrict__ mlpb,
    float* __restrict__ ws, u16* __restrict__ xb16) {
    const int p = blockIdx.x * 256 + threadIdx.x;
    const int y = p >> 7, x = p & 127;
    float* xb = ws + OFF_X;

    if (blockIdx.y == 0) {
        const float w0 = mlpw[0], w1 = mlpw[1], w2 = mlpw[2];
        const float bb = mlpb[0];
#pragma unroll
        for (int c = 0; c < 5; ++c) {
            float a = ws[OFF_OH1 + c * N + p] * w0 +
                      ws[OFF_OH2 + c * N + p] * w1 +
                      ws[OFF_OH3 + c * N + p] * w2 + bb;
            xb[c * N + p] = a;
            xb16[c * N + p] = f2bf(a);
        }
        float pv[9];
#pragma unroll
        for (int i = 0; i < 3; ++i)
#pragma unroll
            for (int j = 0; j < 3; ++j) {
                int yy = y + i - 1, xx = x + j - 1;
                pv[i * 3 + j] = inb(yy, xx) ? pan[yy * 128 + xx] : 0.f;
            }
        float a5[5] = {0, 0, 0, 0, 0};
#pragma unroll
        for (int k = 0; k < 9; ++k)
#pragma unroll
            for (int o = 0; o < 5; ++o)
                a5[o] = fmaf(pv[k], wrp[o * 9 + k], a5[o]);
#pragma unroll
        for (int o = 0; o < 5; ++o) {
            xb[(37 + o) * N + p] = a5[o];
            xb16[(37 + o) * N + p] = f2bf(a5[o]);
        }
    } else {
        const int ob = (blockIdx.y - 1) * 8;
        float uv[8][9];
#pragma unroll
        for (int ic = 0; ic < 8; ++ic)
#pragma unroll
            for (int i = 0; i < 3; ++i)
#pragma unroll
                for (int j = 0; j < 3; ++j) {
                    int yy = y + i - 1, xx = x + j - 1;
                    uv[ic][i * 3 + j] =
                        inb(yy, xx) ? u[ic * N + yy * 128 + xx] : 0.f;
                }
        float acc[8] = {0, 0, 0, 0, 0, 0, 0, 0};
#pragma unroll
        for (int ic = 0; ic < 8; ++ic)
#pragma unroll
            for (int k = 0; k < 9; ++k)
#pragma unroll
                for (int o = 0; o < 8; ++o)
                    acc[o] = fmaf(uv[ic][k], wres[((ob + o) * 8 + ic) * 9 + k],
                                  acc[o]);
#pragma unroll
        for (int o = 0; o < 8; ++o) {
            xb[(5 + ob + o) * N + p] = acc[o];
            xb16[(5 + ob + o) * N + p] = f2bf(acc[o]);
        }
    }
}

// ---------------------------------------------------------------------------
// K4: implicit-GEMM conv on MFMA. C[42x16384] = W[42x378] * im2col(X).
// Block = 64 consecutive px of one row (grid 256); 4 waves, each a 16-px
// n-tile for all MT m-tiles. X tile (42ic x 3row x 66col bf16, 16.6 KB) in
// LDS; B-frag gathered via offset table; A-frags preloaded from slab.
// D layout: col=lane&15 (px), row=quad*4+reg (oc). Acc f32; epilogue does
// bias/skip/relu and writes f32 and/or bf16.
// ---------------------------------------------------------------------------
template <int MT, int OCV, bool BIAS, bool RELU, bool SKIP, bool WF32, bool WB16>
__global__ __launch_bounds__(256, 1) void convm_k(
    const u16* __restrict__ xin, const u16* __restrict__ slab,
    const u16* __restrict__ btab, const float* __restrict__ bs,
    const float* __restrict__ skip, float* __restrict__ of32,
    u16* __restrict__ ob16) {
    __shared__ u16 sX[8316];
    __shared__ __align__(16) u16 sBt[384];
    const int t = threadIdx.x;
    const int y = blockIdx.x >> 1, x0 = (blockIdx.x & 1) << 6;

    for (int i = t; i < 8316; i += 256) {
        int ic = i / 198, rem = i - ic * 198;
        int r = rem / 66, cc = rem - r * 66;
        int gy = y - 1 + r, gx = x0 - 1 + cc;
        sX[i] = inb(gy, gx) ? xin[ic * N + gy * 128 + gx] : (u16)0;
    }
    for (int i = t; i < 384; i += 256) sBt[i] = btab[i];
    __syncthreads();

    const int lane = t & 63, wave = t >> 6;
    const int quad = lane >> 4, col = lane & 15;
    const int ncol = wave * 16 + col;

    union AB { uint4 u; bf16x8 b; };
    AB a[MT][12];
#pragma unroll
    for (int mt = 0; mt < MT; ++mt)
#pragma unroll
        for (int ks = 0; ks < 12; ++ks)
            a[mt][ks].u = ((const uint4*)slab)[(mt * 12 + ks) * 64 + lane];

    f32x4 acc[MT];
#pragma unroll
    for (int mt = 0; mt < MT; ++mt) acc[mt] = {0.f, 0.f, 0.f, 0.f};

#pragma unroll
    for (int ks = 0; ks < 12; ++ks) {
        union { uint4 u; u16 s[8]; } off;
        off.u = *(const uint4*)(sBt + ks * 32 + quad * 8);
        union { u16 s[8]; bf16x8 b; } bv;
#pragma unroll
        for (int j = 0; j < 8; ++j) bv.s[j] = sX[off.s[j] + ncol];
#pragma unroll
        for (int mt = 0; mt < MT; ++mt)
            acc[mt] = __builtin_amdgcn_mfma_f32_16x16x32_bf16(
                a[mt][ks].b, bv.b, acc[mt], 0, 0, 0);
    }

    const int px = y * 128 + x0 + ncol;
#pragma unroll
    for (int mt = 0; mt < MT; ++mt)
#pragma unroll
        for (int reg = 0; reg < 4; ++reg) {
            int oc = mt * 16 + quad * 4 + reg;
            if (oc < OCV) {
                float v = acc[mt][reg];
                if (BIAS) v += bs[oc];
                if (SKIP) v += skip[oc * N + px];
                if (RELU) v = fmaxf(v, 0.f);
                if (WF32) of32[oc * N + px] = v;
                if (WB16) ob16[oc * N + px] = f2bf(v);
            }
        }
}

// ---------------------------------------------------------------------------
extern "C" void kernel_launch(void* const* d_in, const int* in_sizes, int n_in,
                              void* d_out, int out_size, void* d_ws, size_t ws_size,
                              hipStream_t stream) {
    (void)in_sizes; (void)n_in; (void)out_size; (void)ws_size;
    float* ws = (float*)d_ws;
    float* out = (float*)d_out;

    const float* u      = (const float*)d_in[0];
    const float* pan    = (const float*)d_in[1];
    const float* wnlu   = (const float*)d_in[2];
    const float* wnlpan = (const float*)d_in[3];
    const float* gphi   = (const float*)d_in[4];
    const float* gth    = (const float*)d_in[5];
    const float* gg     = (const float*)d_in[6];
    const float* sphi   = (const float*)d_in[7];
    const float* sth    = (const float*)d_in[8];
    const float* sg     = (const float*)d_in[9];
    const float* mphi   = (const float*)d_in[10];
    const float* mth    = (const float*)d_in[11];
    const float* mg     = (const float*)d_in[12];
    const float* mlpw   = (const float*)d_in[13];
    const float* mlpb   = (const float*)d_in[14];
    const float* wres   = (const float*)d_in[15];
    const float* wrp    = (const float*)d_in[16];
    const float* wrecon = (const float*)d_in[17];

    u16* xb16 = (u16*)(ws + OFF_XB16);
    u16* fb16 = (u16*)(ws + OFF_FB16);
    u16* slab = (u16*)(ws + OFF_SLAB);
    u16* btab = (u16*)(ws + OFF_BTAB);

    features_k<<<dim3(N / 256, 2), 256, 0, stream>>>(
        u, pan, wnlu, wnlpan, gphi, gth, gg, sphi, sth, sg, mphi, mth, mg, ws);
    heads_k<<<dim3(128, 3), 256, 0, stream>>>(ws);

    WPtrs wp;
    wp.w[0] = (const float*)d_in[18]; wp.w[1] = (const float*)d_in[20];
    wp.w[2] = (const float*)d_in[22]; wp.w[3] = (const float*)d_in[24];
    wp.w[4] = (const float*)d_in[26]; wp.w[5] = (const float*)d_in[28];
    wp.w[6] = wrecon;
    wprep_k<<<(384 + SLAB_TOT + 255) / 256, 256, 0, stream>>>(wp, slab, btab);

    assemble_k<<<dim3(N / 256, 5), 256, 0, stream>>>(u, pan, wres, wrp, mlpw,
                                                     mlpb, ws, xb16);

    for (int r = 0; r < 3; ++r) {
        const float* b1 = (const float*)d_in[19 + 4 * r];
        const float* b2 = (const float*)d_in[21 + 4 * r];
        // f = relu(conv(x,w1)+b1): bf16 out only
        convm_k<3, 42, true, true, false, false, true>
            <<<256, 256, 0, stream>>>(xb16, slab + (2 * r) * SLAB_RB, btab, b1,
                                      nullptr, nullptr, fb16);
        // x = relu(conv(f,w2)+b2+x): f32 + bf16 out
        convm_k<3, 42, true, true, true, true, true>
            <<<256, 256, 0, stream>>>(fb16, slab + (2 * r + 1) * SLAB_RB, btab,
                                      b2, ws + OFF_X, ws + OFF_X, xb16);
    }
    // recon: 42 -> 8, f32 out
    convm_k<1, 8, false, false, false, true, false>
        <<<256, 256, 0, stream>>>(xb16, slab + SLAB_RC, btab, nullptr, nullptr,
                                  out, nullptr);
}